// Round 1
// baseline (1232.556 us; speedup 1.0000x reference)
//
#include <hip/hip_runtime.h>
#include <math.h>

#define NN 30000
#define EE 480000
#define DIM 128

// ---------------- generic row-GEMM: out[n,:COLS] = in[n,:128] @ W (+bias) ----------------
template<int COLS, int ROWS>
__global__ void gemm_rows(const float* __restrict__ in, const float* __restrict__ W,
                          const float* __restrict__ bias, float* __restrict__ out, int nrows) {
    __shared__ float xs[ROWS][DIM];
    const int tid = threadIdx.x;              // 128
    const int row0 = blockIdx.x * ROWS;
    for (int r = 0; r < ROWS; ++r) {
        int n = row0 + r;
        xs[r][tid] = (n < nrows) ? in[(size_t)n * DIM + tid] : 0.f;
    }
    __syncthreads();
    for (int jc = 0; jc < COLS / DIM; ++jc) {
        float acc[ROWS];
#pragma unroll
        for (int r = 0; r < ROWS; ++r) acc[r] = 0.f;
        const int j = jc * DIM + tid;
        for (int k = 0; k < DIM; ++k) {
            float wv = W[(size_t)k * COLS + j];
#pragma unroll
            for (int r = 0; r < ROWS; ++r) acc[r] = fmaf(xs[r][k], wv, acc[r]);
        }
        float b = bias ? bias[j] : 0.f;
        for (int r = 0; r < ROWS; ++r) {
            int n = row0 + r;
            if (n < nrows) out[(size_t)n * COLS + j] = acc[r] + b;
        }
    }
}

// ---------------- kv[h][f][d] = sum_n phi(k)[n,h,f]*v[n,h,d]; z[h][f] = sum_n phi(k) ----------------
__global__ void kv_reduce(const float* __restrict__ h1, const float* __restrict__ pv,
                          float* __restrict__ kvz) {
    __shared__ float kf_s[DIM];
    __shared__ float v_s[DIM];
    const int tid = threadIdx.x;              // 256
    float acc[8];
#pragma unroll
    for (int i = 0; i < 8; ++i) acc[i] = 0.f;
    float zacc = 0.f;
    const int rpb = (NN + gridDim.x - 1) / gridDim.x;
    const int n0 = blockIdx.x * rpb;
    const int n1 = min(n0 + rpb, NN);
    const int base = tid * 8;                 // idx into 2048 kv entries
    const int hf = base >> 4;                 // h*16+f (constant across the 8)
    const int h = hf >> 4;
    const int d0 = base & 15;
    for (int n = n0; n < n1; ++n) {
        __syncthreads();
        if (tid < 128) {
            float kv = h1[(size_t)n * 384 + 128 + tid];
            kf_s[tid] = kv > 0.f ? kv + 1.f : expf(kv);
        } else {
            v_s[tid - 128] = pv[(size_t)n * 384 + (tid - 128)];
        }
        __syncthreads();
        float kfv = kf_s[hf];
#pragma unroll
        for (int i = 0; i < 8; ++i) acc[i] = fmaf(kfv, v_s[h * 16 + d0 + i], acc[i]);
        if (tid < 128) zacc += kf_s[tid];
    }
#pragma unroll
    for (int i = 0; i < 8; ++i) atomicAdd(&kvz[base + i], acc[i]);
    if (tid < 128) atomicAdd(&kvz[2048 + tid], zacc);
}

// ---------------- att[n,h*16+d] = (qf . kv) / (qf . z + 1e-6) ----------------
__global__ void attn_apply(const float* __restrict__ h1, const float* __restrict__ kvz,
                           float* __restrict__ att, int rpb) {
    __shared__ float kv_s[2048];
    __shared__ float z_s[DIM];
    __shared__ float qf_s[DIM];
    const int tid = threadIdx.x;              // 128
    for (int i = tid; i < 2048; i += 128) kv_s[i] = kvz[i];
    z_s[tid] = kvz[2048 + tid];
    const int n0 = blockIdx.x * rpb;
    const int n1 = min(n0 + rpb, NN);
    const int h = tid >> 4, d = tid & 15;
    for (int n = n0; n < n1; ++n) {
        float qv = h1[(size_t)n * 384 + tid];
        __syncthreads();
        qf_s[tid] = qv > 0.f ? qv + 1.f : expf(qv);
        __syncthreads();
        float num = 0.f, den = 0.f;
#pragma unroll
        for (int f = 0; f < 16; ++f) {
            float q = qf_s[h * 16 + f];
            num = fmaf(q, kv_s[(h * 16 + f) * 16 + d], num);
            den = fmaf(q, z_s[h * 16 + f], den);
        }
        att[(size_t)n * DIM + tid] = num / (den + 1e-6f);
    }
}

// ---------------- vec_dot[n,o] = sum_c v1p[n,c,o]*v2p[n,c,o] (vp recomputed) ----------------
__global__ void vecdot_kernel(const float* __restrict__ vec, const float* __restrict__ Wvp,
                              float* __restrict__ vdot) {
    __shared__ float vs[8][3][DIM];
    const int tid = threadIdx.x;              // 128
    const int n0 = blockIdx.x * 8;
    for (int i = tid; i < 8 * 3 * DIM; i += 128)
        ((float*)vs)[i] = vec[(size_t)n0 * 3 * DIM + i];
    __syncthreads();
    float acc[8] = {};
    for (int c = 0; c < 3; ++c) {
        float a[8] = {}, b[8] = {};
        for (int k = 0; k < DIM; ++k) {
            float w1 = Wvp[(size_t)k * 384 + tid];
            float w2 = Wvp[(size_t)k * 384 + 128 + tid];
#pragma unroll
            for (int r = 0; r < 8; ++r) {
                a[r] = fmaf(vs[r][c][k], w1, a[r]);
                b[r] = fmaf(vs[r][c][k], w2, b[r]);
            }
        }
#pragma unroll
        for (int r = 0; r < 8; ++r) acc[r] = fmaf(a[r], b[r], acc[r]);
    }
    for (int r = 0; r < 8; ++r) vdot[(size_t)(n0 + r) * DIM + tid] = acc[r];
}

// ---------------- att += vdot*o2 + o3 (elementwise) ----------------
__global__ void att2_kernel(float* __restrict__ att, const float* __restrict__ vdot,
                            const float* __restrict__ o) {
    size_t gid = blockIdx.x * (size_t)blockDim.x + threadIdx.x;
    if (gid >= (size_t)NN * DIM) return;
    int n = gid >> 7, j = gid & 127;
    att[gid] += vdot[gid] * o[(size_t)n * 384 + 128 + j] + o[(size_t)n * 384 + 256 + j];
}

// ---------------- edge scatter: agg[dst,c,o] += vec[src,c,o]*vec1[src,o] + evec[e,c]*vec2[src,o] ----------------
__global__ void edge_kernel(const int* __restrict__ eidx, const float* __restrict__ vec,
                            const float* __restrict__ pv, const float* __restrict__ evec,
                            float* __restrict__ agg) {
    size_t gid = blockIdx.x * (size_t)blockDim.x + threadIdx.x;
    int e = (int)(gid >> 7);
    int o = (int)(gid & 127);
    if (e >= EE) return;
    int src = eidx[e], dst = eidx[EE + e];
    float v1 = pv[(size_t)src * 384 + 128 + o];
    float v2 = pv[(size_t)src * 384 + 256 + o];
#pragma unroll
    for (int c = 0; c < 3; ++c) {
        float m = fmaf(vec[((size_t)src * 3 + c) * DIM + o], v1, evec[(size_t)e * 3 + c] * v2);
        atomicAdd(&agg[((size_t)dst * 3 + c) * DIM + o], m);
    }
}

// ---------------- out_x = non_att + (att2 @ W_fco + b_fco)*ew ----------------
__global__ void outx_kernel(const float* __restrict__ att2, const float* __restrict__ Wfco,
                            const float* __restrict__ bfco, const float* __restrict__ h1,
                            const float* __restrict__ ew, float* __restrict__ outx) {
    __shared__ float as[8][DIM];
    const int tid = threadIdx.x;              // 128
    const int n0 = blockIdx.x * 8;
    for (int i = tid; i < 8 * DIM; i += 128)
        ((float*)as)[i] = att2[(size_t)n0 * DIM + i];
    __syncthreads();
    float acc[8] = {};
    for (int k = 0; k < DIM; ++k) {
        float w = Wfco[(size_t)k * DIM + tid];
#pragma unroll
        for (int r = 0; r < 8; ++r) acc[r] = fmaf(as[r][k], w, acc[r]);
    }
    float b = bfco[tid];
    for (int r = 0; r < 8; ++r) {
        int n = n0 + r;
        outx[(size_t)n * DIM + tid] = h1[(size_t)n * 384 + 256 + tid] + (acc[r] + b) * ew[n];
    }
}

// ---------------- delta_vec = v3p*o1 + agg; LN; @ W_equiv ----------------
__global__ void outvec_kernel(const float* __restrict__ vec, const float* __restrict__ Wvp,
                              const float* __restrict__ o, const float* __restrict__ agg,
                              const float* __restrict__ ln_scale, const float* __restrict__ ln_bias,
                              const float* __restrict__ Weq, float* __restrict__ outv) {
    __shared__ float vs[8][DIM];
    __shared__ float dvs[8][DIM];
    __shared__ float stats[8][2];
    const int tid = threadIdx.x;              // 128
    const int r0 = blockIdx.x * 8;            // global (n,c) row index
    for (int i = tid; i < 8 * DIM; i += 128)
        ((float*)vs)[i] = vec[(size_t)r0 * DIM + i];
    __syncthreads();
    float v3[8] = {};
    for (int k = 0; k < DIM; ++k) {
        float w3 = Wvp[(size_t)k * 384 + 256 + tid];
#pragma unroll
        for (int r = 0; r < 8; ++r) v3[r] = fmaf(vs[r][k], w3, v3[r]);
    }
#pragma unroll
    for (int r = 0; r < 8; ++r) {
        int row = r0 + r;
        int n = row / 3;
        dvs[r][tid] = fmaf(v3[r], o[(size_t)n * 384 + tid], agg[(size_t)row * DIM + tid]);
    }
    __syncthreads();
    {   // per-row mean/var: 16 lanes per row
        const int r = tid >> 4, l = tid & 15;
        float s = 0.f, s2 = 0.f;
        for (int k = l; k < DIM; k += 16) { float xv = dvs[r][k]; s += xv; s2 = fmaf(xv, xv, s2); }
#pragma unroll
        for (int w = 8; w >= 1; w >>= 1) { s += __shfl_xor(s, w, 16); s2 += __shfl_xor(s2, w, 16); }
        if (l == 0) {
            float mu = s * (1.f / 128.f);
            float var = s2 * (1.f / 128.f) - mu * mu;
            stats[r][0] = mu;
            stats[r][1] = rsqrtf(var + 1e-5f);
        }
    }
    __syncthreads();
    float sc = ln_scale[tid], bi = ln_bias[tid];
#pragma unroll
    for (int rr = 0; rr < 8; ++rr)
        dvs[rr][tid] = fmaf((dvs[rr][tid] - stats[rr][0]) * stats[rr][1], sc, bi);
    __syncthreads();
    float acc[8] = {};
    for (int k = 0; k < DIM; ++k) {
        float w = Weq[(size_t)k * DIM + tid];
#pragma unroll
        for (int rr = 0; rr < 8; ++rr) acc[rr] = fmaf(dvs[rr][k], w, acc[rr]);
    }
    for (int rr = 0; rr < 8; ++rr)
        outv[(size_t)(r0 + rr) * DIM + tid] = acc[rr];
}

extern "C" void kernel_launch(void* const* d_in, const int* in_sizes, int n_in,
                              void* d_out, int out_size, void* d_ws, size_t ws_size,
                              hipStream_t stream) {
    const float* x          = (const float*)d_in[0];
    const float* vec        = (const float*)d_in[1];
    const float* edge_vec   = (const float*)d_in[2];
    const float* edge_weight= (const float*)d_in[3];
    const float* W_fc1      = (const float*)d_in[4];
    const float* W_fcv      = (const float*)d_in[5];
    const float* b_fcv      = (const float*)d_in[6];
    const float* W_fco      = (const float*)d_in[7];
    const float* b_fco      = (const float*)d_in[8];
    const float* W_out      = (const float*)d_in[9];
    const float* W_vecproj  = (const float*)d_in[10];
    const float* W_equiv    = (const float*)d_in[11];
    const float* ln_scale   = (const float*)d_in[12];
    const float* ln_bias    = (const float*)d_in[13];
    const int*   edge_index = (const int*)d_in[14];

    float* out_x   = (float*)d_out;
    float* out_vec = out_x + (size_t)NN * DIM;

    float* ws   = (float*)d_ws;
    float* h1   = ws;                    // N*384
    float* pv   = h1 + 11520000;         // N*384
    float* att  = pv + 11520000;         // N*128
    float* o    = att + 3840000;         // N*384
    float* vdot = o + 11520000;          // N*128
    float* agg  = vdot + 3840000;        // N*3*128
    float* kvz  = agg + 11520000;        // 2176

    hipMemsetAsync(agg, 0, (11520000 + 2176) * sizeof(float), stream);

    gemm_rows<384, 8><<<NN / 8, 128, 0, stream>>>(x, W_fc1, nullptr, h1, NN);
    gemm_rows<384, 8><<<NN / 8, 128, 0, stream>>>(x, W_fcv, b_fcv, pv, NN);
    kv_reduce<<<256, 256, 0, stream>>>(h1, pv, kvz);
    attn_apply<<<(NN + 31) / 32, 128, 0, stream>>>(h1, kvz, att, 32);
    gemm_rows<384, 8><<<NN / 8, 128, 0, stream>>>(att, W_out, nullptr, o, NN);
    vecdot_kernel<<<NN / 8, 128, 0, stream>>>(vec, W_vecproj, vdot);
    att2_kernel<<<(NN * DIM) / 256, 256, 0, stream>>>(att, vdot, o);
    edge_kernel<<<(EE * 128) / 256, 256, 0, stream>>>(edge_index, vec, pv, edge_vec, agg);
    outx_kernel<<<NN / 8, 128, 0, stream>>>(att, W_fco, b_fco, h1, edge_weight, out_x);
    outvec_kernel<<<(NN * 3) / 8, 128, 0, stream>>>(vec, W_vecproj, o, agg, ln_scale, ln_bias,
                                                    W_equiv, out_vec);
}

// Round 2
// 949.971 us; speedup vs baseline: 1.2975x; 1.2975x over previous
//
#include <hip/hip_runtime.h>
#include <math.h>

#define NN 30000
#define EE 480000
#define DIM 128

// ---------------- generic row-GEMM: out[n,:COLS] = in[n,:128] @ W (+bias) ----------------
template<int COLS, int ROWS>
__global__ void gemm_rows(const float* __restrict__ in, const float* __restrict__ W,
                          const float* __restrict__ bias, float* __restrict__ out, int nrows) {
    __shared__ float xs[ROWS][DIM];
    const int tid = threadIdx.x;              // 128
    const int row0 = blockIdx.x * ROWS;
    for (int r = 0; r < ROWS; ++r) {
        int n = row0 + r;
        xs[r][tid] = (n < nrows) ? in[(size_t)n * DIM + tid] : 0.f;
    }
    __syncthreads();
    for (int jc = 0; jc < COLS / DIM; ++jc) {
        float acc[ROWS];
#pragma unroll
        for (int r = 0; r < ROWS; ++r) acc[r] = 0.f;
        const int j = jc * DIM + tid;
        for (int k = 0; k < DIM; ++k) {
            float wv = W[(size_t)k * COLS + j];
#pragma unroll
            for (int r = 0; r < ROWS; ++r) acc[r] = fmaf(xs[r][k], wv, acc[r]);
        }
        float b = bias ? bias[j] : 0.f;
        for (int r = 0; r < ROWS; ++r) {
            int n = row0 + r;
            if (n < nrows) out[(size_t)n * COLS + j] = acc[r] + b;
        }
    }
}

// ---------------- kv[h][f][d] = sum_n phi(k)[n,h,f]*v[n,h,d]; z[h][f] = sum_n phi(k) ----------------
__global__ void kv_reduce(const float* __restrict__ h1, const float* __restrict__ pv,
                          float* __restrict__ kvz) {
    __shared__ float kf_s[DIM];
    __shared__ float v_s[DIM];
    const int tid = threadIdx.x;              // 256
    float acc[8];
#pragma unroll
    for (int i = 0; i < 8; ++i) acc[i] = 0.f;
    float zacc = 0.f;
    const int rpb = (NN + gridDim.x - 1) / gridDim.x;
    const int n0 = blockIdx.x * rpb;
    const int n1 = min(n0 + rpb, NN);
    const int base = tid * 8;                 // idx into 2048 kv entries
    const int hf = base >> 4;                 // h*16+f (constant across the 8)
    const int h = hf >> 4;
    const int d0 = base & 15;
    for (int n = n0; n < n1; ++n) {
        __syncthreads();
        if (tid < 128) {
            float kv = h1[(size_t)n * 384 + 128 + tid];
            kf_s[tid] = kv > 0.f ? kv + 1.f : expf(kv);
        } else {
            v_s[tid - 128] = pv[(size_t)n * 384 + (tid - 128)];
        }
        __syncthreads();
        float kfv = kf_s[hf];
#pragma unroll
        for (int i = 0; i < 8; ++i) acc[i] = fmaf(kfv, v_s[h * 16 + d0 + i], acc[i]);
        if (tid < 128) zacc += kf_s[tid];
    }
#pragma unroll
    for (int i = 0; i < 8; ++i) atomicAdd(&kvz[base + i], acc[i]);
    if (tid < 128) atomicAdd(&kvz[2048 + tid], zacc);
}

// ---------------- att[n,h*16+d] = (qf . kv) / (qf . z + 1e-6) ----------------
__global__ void attn_apply(const float* __restrict__ h1, const float* __restrict__ kvz,
                           float* __restrict__ att, int rpb) {
    __shared__ float kv_s[2048];
    __shared__ float z_s[DIM];
    __shared__ float qf_s[DIM];
    const int tid = threadIdx.x;              // 128
    for (int i = tid; i < 2048; i += 128) kv_s[i] = kvz[i];
    z_s[tid] = kvz[2048 + tid];
    const int n0 = blockIdx.x * rpb;
    const int n1 = min(n0 + rpb, NN);
    const int h = tid >> 4, d = tid & 15;
    for (int n = n0; n < n1; ++n) {
        float qv = h1[(size_t)n * 384 + tid];
        __syncthreads();
        qf_s[tid] = qv > 0.f ? qv + 1.f : expf(qv);
        __syncthreads();
        float num = 0.f, den = 0.f;
#pragma unroll
        for (int f = 0; f < 16; ++f) {
            float q = qf_s[h * 16 + f];
            num = fmaf(q, kv_s[(h * 16 + f) * 16 + d], num);
            den = fmaf(q, z_s[h * 16 + f], den);
        }
        att[(size_t)n * DIM + tid] = num / (den + 1e-6f);
    }
}

// ---------------- vec_dot[n,o] = sum_c v1p[n,c,o]*v2p[n,c,o] (vp recomputed) ----------------
__global__ void vecdot_kernel(const float* __restrict__ vec, const float* __restrict__ Wvp,
                              float* __restrict__ vdot) {
    __shared__ float vs[8][3][DIM];
    const int tid = threadIdx.x;              // 128
    const int n0 = blockIdx.x * 8;
    for (int i = tid; i < 8 * 3 * DIM; i += 128)
        ((float*)vs)[i] = vec[(size_t)n0 * 3 * DIM + i];
    __syncthreads();
    float acc[8] = {};
    for (int c = 0; c < 3; ++c) {
        float a[8] = {}, b[8] = {};
        for (int k = 0; k < DIM; ++k) {
            float w1 = Wvp[(size_t)k * 384 + tid];
            float w2 = Wvp[(size_t)k * 384 + 128 + tid];
#pragma unroll
            for (int r = 0; r < 8; ++r) {
                a[r] = fmaf(vs[r][c][k], w1, a[r]);
                b[r] = fmaf(vs[r][c][k], w2, b[r]);
            }
        }
#pragma unroll
        for (int r = 0; r < 8; ++r) acc[r] = fmaf(a[r], b[r], acc[r]);
    }
    for (int r = 0; r < 8; ++r) vdot[(size_t)(n0 + r) * DIM + tid] = acc[r];
}

// ---------------- edge CSR build: histogram ----------------
__global__ void hist_kernel(const int* __restrict__ eidx, int* __restrict__ cnt) {
    int e = blockIdx.x * 256 + threadIdx.x;
    if (e < EE) atomicAdd(&cnt[eidx[EE + e]], 1);
}

// ---------------- edge CSR build: single-block exclusive scan of cnt -> off, pos ----------------
__global__ void scan_kernel(const int* __restrict__ cnt, int* __restrict__ off,
                            int* __restrict__ pos) {
    __shared__ int tsum[1024];
    const int tid = threadIdx.x;              // 1024
    const int PER = 30;                       // 1024*30 >= NN
    const int base = tid * PER;
    int local[PER];
    int s = 0;
#pragma unroll
    for (int i = 0; i < PER; ++i) {
        int idx = base + i;
        int c = (idx < NN) ? cnt[idx] : 0;
        local[i] = s;
        s += c;
    }
    tsum[tid] = s;
    __syncthreads();
    // Hillis-Steele inclusive scan over 1024 thread sums
    for (int d = 1; d < 1024; d <<= 1) {
        int v = (tid >= d) ? tsum[tid - d] : 0;
        __syncthreads();
        tsum[tid] += v;
        __syncthreads();
    }
    const int carry = (tid == 0) ? 0 : tsum[tid - 1];
#pragma unroll
    for (int i = 0; i < PER; ++i) {
        int idx = base + i;
        if (idx < NN) {
            int v = carry + local[i];
            off[idx] = v;
            pos[idx] = v;
        }
    }
    if (tid == 1023) off[NN] = tsum[1023];
}

// ---------------- edge CSR build: scatter edge ids into dst-sorted order ----------------
__global__ void scatter_kernel(const int* __restrict__ eidx, int* __restrict__ pos,
                               int* __restrict__ sorted) {
    int e = blockIdx.x * 256 + threadIdx.x;
    if (e >= EE) return;
    int dst = eidx[EE + e];
    int p = atomicAdd(&pos[dst], 1);
    sorted[p] = e;
}

// ---------------- segmented gather-reduce: one block per dst ----------------
__global__ void edge_agg_kernel(const int* __restrict__ eidx, const int* __restrict__ off,
                                const int* __restrict__ sorted, const float* __restrict__ vec,
                                const float* __restrict__ pv, const float* __restrict__ evec,
                                float* __restrict__ agg) {
    __shared__ int srcs[128];
    __shared__ float evs[128][3];
    const int dst = blockIdx.x;
    const int o = threadIdx.x;                // 128
    const int j0 = off[dst], j1 = off[dst + 1];
    float a0 = 0.f, a1 = 0.f, a2 = 0.f;
    for (int jt = j0; jt < j1; jt += 128) {
        const int m = min(128, j1 - jt);
        if (o < m) {
            int e = sorted[jt + o];
            srcs[o] = eidx[e];
            evs[o][0] = evec[(size_t)e * 3 + 0];
            evs[o][1] = evec[(size_t)e * 3 + 1];
            evs[o][2] = evec[(size_t)e * 3 + 2];
        }
        __syncthreads();
        for (int jj = 0; jj < m; ++jj) {
            int src = srcs[jj];
            float v1 = pv[(size_t)src * 384 + 128 + o];
            float v2 = pv[(size_t)src * 384 + 256 + o];
            a0 = fmaf(vec[((size_t)src * 3 + 0) * DIM + o], v1, fmaf(evs[jj][0], v2, a0));
            a1 = fmaf(vec[((size_t)src * 3 + 1) * DIM + o], v1, fmaf(evs[jj][1], v2, a1));
            a2 = fmaf(vec[((size_t)src * 3 + 2) * DIM + o], v1, fmaf(evs[jj][2], v2, a2));
        }
        __syncthreads();
    }
    agg[((size_t)dst * 3 + 0) * DIM + o] = a0;
    agg[((size_t)dst * 3 + 1) * DIM + o] = a1;
    agg[((size_t)dst * 3 + 2) * DIM + o] = a2;
}

// ---------------- out_x = non_att + ((att + vdot*o2 + o3) @ W_fco + b_fco)*ew ----------------
__global__ void outx_kernel(const float* __restrict__ att, const float* __restrict__ vdot,
                            const float* __restrict__ o, const float* __restrict__ Wfco,
                            const float* __restrict__ bfco, const float* __restrict__ h1,
                            const float* __restrict__ ew, float* __restrict__ outx) {
    __shared__ float as[8][DIM];
    const int tid = threadIdx.x;              // 128
    const int n0 = blockIdx.x * 8;
    for (int i = tid; i < 8 * DIM; i += 128) {
        int n = n0 + (i >> 7), j = i & 127;
        ((float*)as)[i] = att[(size_t)n * DIM + j]
                        + vdot[(size_t)n * DIM + j] * o[(size_t)n * 384 + 128 + j]
                        + o[(size_t)n * 384 + 256 + j];
    }
    __syncthreads();
    float acc[8] = {};
    for (int k = 0; k < DIM; ++k) {
        float w = Wfco[(size_t)k * DIM + tid];
#pragma unroll
        for (int r = 0; r < 8; ++r) acc[r] = fmaf(as[r][k], w, acc[r]);
    }
    float b = bfco[tid];
    for (int r = 0; r < 8; ++r) {
        int n = n0 + r;
        outx[(size_t)n * DIM + tid] = h1[(size_t)n * 384 + 256 + tid] + (acc[r] + b) * ew[n];
    }
}

// ---------------- delta_vec = v3p*o1 + agg; LN; @ W_equiv ----------------
__global__ void outvec_kernel(const float* __restrict__ vec, const float* __restrict__ Wvp,
                              const float* __restrict__ o, const float* __restrict__ agg,
                              const float* __restrict__ ln_scale, const float* __restrict__ ln_bias,
                              const float* __restrict__ Weq, float* __restrict__ outv) {
    __shared__ float vs[8][DIM];
    __shared__ float dvs[8][DIM];
    __shared__ float stats[8][2];
    const int tid = threadIdx.x;              // 128
    const int r0 = blockIdx.x * 8;            // global (n,c) row index
    for (int i = tid; i < 8 * DIM; i += 128)
        ((float*)vs)[i] = vec[(size_t)r0 * DIM + i];
    __syncthreads();
    float v3[8] = {};
    for (int k = 0; k < DIM; ++k) {
        float w3 = Wvp[(size_t)k * 384 + 256 + tid];
#pragma unroll
        for (int r = 0; r < 8; ++r) v3[r] = fmaf(vs[r][k], w3, v3[r]);
    }
#pragma unroll
    for (int r = 0; r < 8; ++r) {
        int row = r0 + r;
        int n = row / 3;
        dvs[r][tid] = fmaf(v3[r], o[(size_t)n * 384 + tid], agg[(size_t)row * DIM + tid]);
    }
    __syncthreads();
    {   // per-row mean/var: 16 lanes per row
        const int r = tid >> 4, l = tid & 15;
        float s = 0.f, s2 = 0.f;
        for (int k = l; k < DIM; k += 16) { float xv = dvs[r][k]; s += xv; s2 = fmaf(xv, xv, s2); }
#pragma unroll
        for (int w = 8; w >= 1; w >>= 1) { s += __shfl_xor(s, w, 16); s2 += __shfl_xor(s2, w, 16); }
        if (l == 0) {
            float mu = s * (1.f / 128.f);
            float var = s2 * (1.f / 128.f) - mu * mu;
            stats[r][0] = mu;
            stats[r][1] = rsqrtf(var + 1e-5f);
        }
    }
    __syncthreads();
    float sc = ln_scale[tid], bi = ln_bias[tid];
#pragma unroll
    for (int rr = 0; rr < 8; ++rr)
        dvs[rr][tid] = fmaf((dvs[rr][tid] - stats[rr][0]) * stats[rr][1], sc, bi);
    __syncthreads();
    float acc[8] = {};
    for (int k = 0; k < DIM; ++k) {
        float w = Weq[(size_t)k * DIM + tid];
#pragma unroll
        for (int rr = 0; rr < 8; ++rr) acc[rr] = fmaf(dvs[rr][k], w, acc[rr]);
    }
    for (int rr = 0; rr < 8; ++rr)
        outv[(size_t)(r0 + rr) * DIM + tid] = acc[rr];
}

extern "C" void kernel_launch(void* const* d_in, const int* in_sizes, int n_in,
                              void* d_out, int out_size, void* d_ws, size_t ws_size,
                              hipStream_t stream) {
    const float* x          = (const float*)d_in[0];
    const float* vec        = (const float*)d_in[1];
    const float* edge_vec   = (const float*)d_in[2];
    const float* edge_weight= (const float*)d_in[3];
    const float* W_fc1      = (const float*)d_in[4];
    const float* W_fcv      = (const float*)d_in[5];
    const float* b_fcv      = (const float*)d_in[6];
    const float* W_fco      = (const float*)d_in[7];
    const float* b_fco      = (const float*)d_in[8];
    const float* W_out      = (const float*)d_in[9];
    const float* W_vecproj  = (const float*)d_in[10];
    const float* W_equiv    = (const float*)d_in[11];
    const float* ln_scale   = (const float*)d_in[12];
    const float* ln_bias    = (const float*)d_in[13];
    const int*   edge_index = (const int*)d_in[14];

    float* out_x   = (float*)d_out;
    float* out_vec = out_x + (size_t)NN * DIM;

    float* ws   = (float*)d_ws;
    float* h1   = ws;                    // N*384
    float* pv   = h1 + 11520000;         // N*384
    float* att  = pv + 11520000;         // N*128
    float* o    = att + 3840000;         // N*384
    float* vdot = o + 11520000;          // N*128
    float* agg  = vdot + 3840000;        // N*3*128
    float* kvz  = agg + 11520000;        // 2176
    int*   cnt    = (int*)(kvz + 2176);  // N
    int*   off    = cnt + NN;            // N+1
    int*   pos    = off + NN + 1;        // N
    int*   sorted = pos + NN;            // E

    hipMemsetAsync(kvz, 0, 2176 * sizeof(float), stream);
    hipMemsetAsync(cnt, 0, NN * sizeof(int), stream);

    // CSR build (only depends on edge_index)
    hist_kernel<<<(EE + 255) / 256, 256, 0, stream>>>(edge_index, cnt);
    scan_kernel<<<1, 1024, 0, stream>>>(cnt, off, pos);
    scatter_kernel<<<(EE + 255) / 256, 256, 0, stream>>>(edge_index, pos, sorted);

    gemm_rows<384, 8><<<NN / 8, 128, 0, stream>>>(x, W_fc1, nullptr, h1, NN);
    gemm_rows<384, 8><<<NN / 8, 128, 0, stream>>>(x, W_fcv, b_fcv, pv, NN);
    kv_reduce<<<512, 256, 0, stream>>>(h1, pv, kvz);
    attn_apply<<<(NN + 31) / 32, 128, 0, stream>>>(h1, kvz, att, 32);
    gemm_rows<384, 8><<<NN / 8, 128, 0, stream>>>(att, W_out, nullptr, o, NN);
    vecdot_kernel<<<NN / 8, 128, 0, stream>>>(vec, W_vecproj, vdot);
    edge_agg_kernel<<<NN, 128, 0, stream>>>(edge_index, off, sorted, vec, pv, edge_vec, agg);
    outx_kernel<<<NN / 8, 128, 0, stream>>>(att, vdot, o, W_fco, b_fco, h1, edge_weight, out_x);
    outvec_kernel<<<(NN * 3) / 8, 128, 0, stream>>>(vec, W_vecproj, o, agg, ln_scale, ln_bias,
                                                    W_equiv, out_vec);
}

// Round 3
// 920.773 us; speedup vs baseline: 1.3386x; 1.0317x over previous
//
#include <hip/hip_runtime.h>
#include <math.h>

#define NN 30000
#define EE 480000
#define DIM 128

// ---------------- generic row-GEMM: out[n,:COLS] = in[n,:128] @ W (+bias) ----------------
template<int COLS, int ROWS>
__global__ void gemm_rows(const float* __restrict__ in, const float* __restrict__ W,
                          const float* __restrict__ bias, float* __restrict__ out, int nrows) {
    __shared__ float xs[ROWS][DIM];
    const int tid = threadIdx.x;              // 128
    const int row0 = blockIdx.x * ROWS;
    for (int r = 0; r < ROWS; ++r) {
        int n = row0 + r;
        xs[r][tid] = (n < nrows) ? in[(size_t)n * DIM + tid] : 0.f;
    }
    __syncthreads();
    for (int jc = 0; jc < COLS / DIM; ++jc) {
        float acc[ROWS];
#pragma unroll
        for (int r = 0; r < ROWS; ++r) acc[r] = 0.f;
        const int j = jc * DIM + tid;
        for (int k = 0; k < DIM; ++k) {
            float wv = W[(size_t)k * COLS + j];
#pragma unroll
            for (int r = 0; r < ROWS; ++r) acc[r] = fmaf(xs[r][k], wv, acc[r]);
        }
        float b = bias ? bias[j] : 0.f;
        for (int r = 0; r < ROWS; ++r) {
            int n = row0 + r;
            if (n < nrows) out[(size_t)n * COLS + j] = acc[r] + b;
        }
    }
}

// ---------------- kv[h][f][d] = sum_n phi(k)[n,h,f]*v[n,h,d]; z[h][f] = sum_n phi(k) -------
// 8-row tiles: one barrier pair per 8 rows instead of per row.
__global__ void kv_reduce(const float* __restrict__ h1, const float* __restrict__ pv,
                          float* __restrict__ kvz) {
    __shared__ float kf_s[8][DIM];
    __shared__ float v_s[8][DIM];
    const int tid = threadIdx.x;              // 256
    float acc[8];
#pragma unroll
    for (int i = 0; i < 8; ++i) acc[i] = 0.f;
    float zacc = 0.f;
    const int rpb = (NN + gridDim.x - 1) / gridDim.x;
    const int n0 = blockIdx.x * rpb;
    const int n1 = min(n0 + rpb, NN);
    const int base = tid * 8;                 // idx into 2048 kv entries
    const int hf = base >> 4;                 // h*16+f
    const int h = hf >> 4;
    const int d0 = base & 15;
    for (int nt = n0; nt < n1; nt += 8) {
        const int m = min(8, n1 - nt);
#pragma unroll
        for (int r = 0; r < 8; ++r) {
            if (r < m) {
                int n = nt + r;
                if (tid < 128) {
                    float kv = h1[(size_t)n * 384 + 128 + tid];
                    kf_s[r][tid] = kv > 0.f ? kv + 1.f : expf(kv);
                } else {
                    v_s[r][tid - 128] = pv[(size_t)n * 384 + (tid - 128)];
                }
            } else {
                if (tid < 128) kf_s[r][tid] = 0.f; else v_s[r][tid - 128] = 0.f;
            }
        }
        __syncthreads();
#pragma unroll
        for (int r = 0; r < 8; ++r) {
            float kfv = kf_s[r][hf];
#pragma unroll
            for (int i = 0; i < 8; ++i) acc[i] = fmaf(kfv, v_s[r][h * 16 + d0 + i], acc[i]);
            if (tid < 128) zacc += kf_s[r][tid];
        }
        __syncthreads();
    }
#pragma unroll
    for (int i = 0; i < 8; ++i) atomicAdd(&kvz[base + i], acc[i]);
    if (tid < 128) atomicAdd(&kvz[2048 + tid], zacc);
}

// ---------------- att[n,h*16+d] = (qf . kv) / (qf . z + 1e-6), 8 rows per block ------------
__global__ void attn_apply(const float* __restrict__ h1, const float* __restrict__ kvz,
                           float* __restrict__ att) {
    __shared__ float kv_s[8 * 16 * 17];       // [hf*17 + d] padded stride
    __shared__ float z_s[DIM];
    __shared__ float qf_s[8][DIM];
    const int tid = threadIdx.x;              // 128
    const int n0 = blockIdx.x * 8;
    for (int i = tid; i < 2048; i += 128) {
        int hf = i >> 4, d = i & 15;
        kv_s[hf * 17 + d] = kvz[i];
    }
    z_s[tid] = kvz[2048 + tid];
#pragma unroll
    for (int r = 0; r < 8; ++r) {
        float qv = h1[(size_t)(n0 + r) * 384 + tid];
        qf_s[r][tid] = qv > 0.f ? qv + 1.f : expf(qv);
    }
    __syncthreads();
    const int h = tid >> 4, d = tid & 15;
#pragma unroll
    for (int r = 0; r < 8; ++r) {
        float num = 0.f, den = 0.f;
#pragma unroll
        for (int f = 0; f < 16; ++f) {
            float q = qf_s[r][h * 16 + f];
            num = fmaf(q, kv_s[(h * 16 + f) * 17 + d], num);
            den = fmaf(q, z_s[h * 16 + f], den);
        }
        att[(size_t)(n0 + r) * DIM + tid] = num / (den + 1e-6f);
    }
}

// ---------------- vec_dot + P-pack:  P[n] = [vec2 | vec[:,0]*vec1 | vec[:,1]*vec1 | vec[:,2]*vec1]
__global__ void vecdot_kernel(const float* __restrict__ vec, const float* __restrict__ Wvp,
                              const float* __restrict__ pv, float* __restrict__ vdot,
                              float* __restrict__ P) {
    __shared__ float vs[8][3][DIM];
    const int tid = threadIdx.x;              // 128
    const int n0 = blockIdx.x * 8;
    for (int i = tid; i < 8 * 3 * DIM; i += 128)
        ((float*)vs)[i] = vec[(size_t)n0 * 3 * DIM + i];
    __syncthreads();
    float acc[8] = {};
    for (int c = 0; c < 3; ++c) {
        float a[8] = {}, b[8] = {};
        for (int k = 0; k < DIM; ++k) {
            float w1 = Wvp[(size_t)k * 384 + tid];
            float w2 = Wvp[(size_t)k * 384 + 128 + tid];
#pragma unroll
            for (int r = 0; r < 8; ++r) {
                a[r] = fmaf(vs[r][c][k], w1, a[r]);
                b[r] = fmaf(vs[r][c][k], w2, b[r]);
            }
        }
#pragma unroll
        for (int r = 0; r < 8; ++r) acc[r] = fmaf(a[r], b[r], acc[r]);
    }
#pragma unroll
    for (int r = 0; r < 8; ++r) {
        int n = n0 + r;
        vdot[(size_t)n * DIM + tid] = acc[r];
        float v1 = pv[(size_t)n * 384 + 128 + tid];
        float v2 = pv[(size_t)n * 384 + 256 + tid];
        float* pr = P + (size_t)n * 512;
        pr[tid]       = v2;
        pr[128 + tid] = vs[r][0][tid] * v1;
        pr[256 + tid] = vs[r][1][tid] * v1;
        pr[384 + tid] = vs[r][2][tid] * v1;
    }
}

// ---------------- edge CSR build ----------------
__global__ void hist_kernel(const int* __restrict__ eidx, int* __restrict__ cnt) {
    int e = blockIdx.x * 256 + threadIdx.x;
    if (e < EE) atomicAdd(&cnt[eidx[EE + e]], 1);
}

__global__ void scan_kernel(const int* __restrict__ cnt, int* __restrict__ off,
                            int* __restrict__ pos) {
    __shared__ int tsum[1024];
    const int tid = threadIdx.x;              // 1024
    const int PER = 30;
    const int base = tid * PER;
    int local[PER];
    int s = 0;
#pragma unroll
    for (int i = 0; i < PER; ++i) {
        int idx = base + i;
        int c = (idx < NN) ? cnt[idx] : 0;
        local[i] = s;
        s += c;
    }
    tsum[tid] = s;
    __syncthreads();
    for (int d = 1; d < 1024; d <<= 1) {
        int v = (tid >= d) ? tsum[tid - d] : 0;
        __syncthreads();
        tsum[tid] += v;
        __syncthreads();
    }
    const int carry = (tid == 0) ? 0 : tsum[tid - 1];
#pragma unroll
    for (int i = 0; i < PER; ++i) {
        int idx = base + i;
        if (idx < NN) {
            int v = carry + local[i];
            off[idx] = v;
            pos[idx] = v;
        }
    }
    if (tid == 1023) off[NN] = tsum[1023];
}

__global__ void scatter_kernel(const int* __restrict__ eidx, int* __restrict__ pos,
                               int* __restrict__ se, int* __restrict__ ssrc) {
    int e = blockIdx.x * 256 + threadIdx.x;
    if (e >= EE) return;
    int dst = eidx[EE + e];
    int p = atomicAdd(&pos[dst], 1);
    se[p] = e;
    ssrc[p] = eidx[e];
}

// ---------------- segmented gather-reduce: one block (2 groups) per dst --------------------
__global__ __launch_bounds__(256) void edge_agg_kernel(
        const int* __restrict__ off, const int* __restrict__ ssrc,
        const int* __restrict__ se, const float* __restrict__ evec,
        const float* __restrict__ P, float* __restrict__ agg) {
    __shared__ int srcs[128];
    __shared__ float evs[3][128];
    __shared__ float part[3][128];
    const int dst = blockIdx.x;
    const int tid = threadIdx.x;              // 256
    const int g = tid >> 7, o = tid & 127;
    const int j0 = off[dst], j1 = off[dst + 1];
    float a0 = 0.f, a1 = 0.f, a2 = 0.f;
    for (int jt = j0; jt < j1; jt += 128) {
        const int m = min(128, j1 - jt);
        if (tid < m) {
            srcs[tid] = ssrc[jt + tid];
            int e = se[jt + tid];
            evs[0][tid] = evec[(size_t)e * 3 + 0];
            evs[1][tid] = evec[(size_t)e * 3 + 1];
            evs[2][tid] = evec[(size_t)e * 3 + 2];
        }
        __syncthreads();
        for (int jj = g; jj < m; jj += 2) {
            const float* p = P + (size_t)srcs[jj] * 512;
            float b = p[o];
            a0 += fmaf(evs[0][jj], b, p[128 + o]);
            a1 += fmaf(evs[1][jj], b, p[256 + o]);
            a2 += fmaf(evs[2][jj], b, p[384 + o]);
        }
        __syncthreads();
    }
    if (g == 1) { part[0][o] = a0; part[1][o] = a1; part[2][o] = a2; }
    __syncthreads();
    if (g == 0) {
        a0 += part[0][o]; a1 += part[1][o]; a2 += part[2][o];
        agg[((size_t)dst * 3 + 0) * DIM + o] = a0;
        agg[((size_t)dst * 3 + 1) * DIM + o] = a1;
        agg[((size_t)dst * 3 + 2) * DIM + o] = a2;
    }
}

// ---------------- out_x = non_att + ((att + vdot*o2 + o3) @ W_fco + b_fco)*ew --------------
__global__ void outx_kernel(const float* __restrict__ att, const float* __restrict__ vdot,
                            const float* __restrict__ o, const float* __restrict__ Wfco,
                            const float* __restrict__ bfco, const float* __restrict__ h1,
                            const float* __restrict__ ew, float* __restrict__ outx) {
    __shared__ float as[8][DIM];
    const int tid = threadIdx.x;              // 128
    const int n0 = blockIdx.x * 8;
    for (int i = tid; i < 8 * DIM; i += 128) {
        int n = n0 + (i >> 7), j = i & 127;
        ((float*)as)[i] = att[(size_t)n * DIM + j]
                        + vdot[(size_t)n * DIM + j] * o[(size_t)n * 384 + 128 + j]
                        + o[(size_t)n * 384 + 256 + j];
    }
    __syncthreads();
    float acc[8] = {};
    for (int k = 0; k < DIM; ++k) {
        float w = Wfco[(size_t)k * DIM + tid];
#pragma unroll
        for (int r = 0; r < 8; ++r) acc[r] = fmaf(as[r][k], w, acc[r]);
    }
    float b = bfco[tid];
    for (int r = 0; r < 8; ++r) {
        int n = n0 + r;
        outx[(size_t)n * DIM + tid] = h1[(size_t)n * 384 + 256 + tid] + (acc[r] + b) * ew[n];
    }
}

// ---------------- delta_vec = v3p*o1 + agg; LN; @ W_equiv ----------------
__global__ void outvec_kernel(const float* __restrict__ vec, const float* __restrict__ Wvp,
                              const float* __restrict__ o, const float* __restrict__ agg,
                              const float* __restrict__ ln_scale, const float* __restrict__ ln_bias,
                              const float* __restrict__ Weq, float* __restrict__ outv) {
    __shared__ float vs[8][DIM];
    __shared__ float dvs[8][DIM];
    __shared__ float stats[8][2];
    const int tid = threadIdx.x;              // 128
    const int r0 = blockIdx.x * 8;            // global (n,c) row index
    for (int i = tid; i < 8 * DIM; i += 128)
        ((float*)vs)[i] = vec[(size_t)r0 * DIM + i];
    __syncthreads();
    float v3[8] = {};
    for (int k = 0; k < DIM; ++k) {
        float w3 = Wvp[(size_t)k * 384 + 256 + tid];
#pragma unroll
        for (int r = 0; r < 8; ++r) v3[r] = fmaf(vs[r][k], w3, v3[r]);
    }
#pragma unroll
    for (int r = 0; r < 8; ++r) {
        int row = r0 + r;
        int n = row / 3;
        dvs[r][tid] = fmaf(v3[r], o[(size_t)n * 384 + tid], agg[(size_t)row * DIM + tid]);
    }
    __syncthreads();
    {
        const int r = tid >> 4, l = tid & 15;
        float s = 0.f, s2 = 0.f;
        for (int k = l; k < DIM; k += 16) { float xv = dvs[r][k]; s += xv; s2 = fmaf(xv, xv, s2); }
#pragma unroll
        for (int w = 8; w >= 1; w >>= 1) { s += __shfl_xor(s, w, 16); s2 += __shfl_xor(s2, w, 16); }
        if (l == 0) {
            float mu = s * (1.f / 128.f);
            float var = s2 * (1.f / 128.f) - mu * mu;
            stats[r][0] = mu;
            stats[r][1] = rsqrtf(var + 1e-5f);
        }
    }
    __syncthreads();
    float sc = ln_scale[tid], bi = ln_bias[tid];
#pragma unroll
    for (int rr = 0; rr < 8; ++rr)
        dvs[rr][tid] = fmaf((dvs[rr][tid] - stats[rr][0]) * stats[rr][1], sc, bi);
    __syncthreads();
    float acc[8] = {};
    for (int k = 0; k < DIM; ++k) {
        float w = Weq[(size_t)k * DIM + tid];
#pragma unroll
        for (int rr = 0; rr < 8; ++rr) acc[rr] = fmaf(dvs[rr][k], w, acc[rr]);
    }
    for (int rr = 0; rr < 8; ++rr)
        outv[(size_t)(r0 + rr) * DIM + tid] = acc[rr];
}

extern "C" void kernel_launch(void* const* d_in, const int* in_sizes, int n_in,
                              void* d_out, int out_size, void* d_ws, size_t ws_size,
                              hipStream_t stream) {
    const float* x          = (const float*)d_in[0];
    const float* vec        = (const float*)d_in[1];
    const float* edge_vec   = (const float*)d_in[2];
    const float* edge_weight= (const float*)d_in[3];
    const float* W_fc1      = (const float*)d_in[4];
    const float* W_fcv      = (const float*)d_in[5];
    const float* b_fcv      = (const float*)d_in[6];
    const float* W_fco      = (const float*)d_in[7];
    const float* b_fco      = (const float*)d_in[8];
    const float* W_out      = (const float*)d_in[9];
    const float* W_vecproj  = (const float*)d_in[10];
    const float* W_equiv    = (const float*)d_in[11];
    const float* ln_scale   = (const float*)d_in[12];
    const float* ln_bias    = (const float*)d_in[13];
    const int*   edge_index = (const int*)d_in[14];

    float* out_x   = (float*)d_out;
    float* out_vec = out_x + (size_t)NN * DIM;
    // P (N x 512 floats) aliases d_out: fully written by vecdot, fully consumed by
    // edge_agg, then overwritten by outx/outvec (stream-ordered, safe).
    float* P = (float*)d_out;

    float* ws   = (float*)d_ws;
    float* h1   = ws;                    // N*384
    float* pv   = h1 + 11520000;         // N*384
    float* att  = pv + 11520000;         // N*128
    float* o    = att + 3840000;         // N*384
    float* vdot = o + 11520000;          // N*128
    float* agg  = vdot + 3840000;        // N*3*128
    float* kvz  = agg + 11520000;        // 2176
    int*   cnt    = (int*)(kvz + 2176);  // N
    int*   off    = cnt + NN;            // N+1
    int*   pos    = off + NN + 1;        // N
    int*   se     = pos + NN;            // E
    int*   ssrc   = se + EE;             // E

    hipMemsetAsync(kvz, 0, 2176 * sizeof(float), stream);
    hipMemsetAsync(cnt, 0, NN * sizeof(int), stream);

    // CSR build (depends only on edge_index)
    hist_kernel<<<(EE + 255) / 256, 256, 0, stream>>>(edge_index, cnt);
    scan_kernel<<<1, 1024, 0, stream>>>(cnt, off, pos);
    scatter_kernel<<<(EE + 255) / 256, 256, 0, stream>>>(edge_index, pos, se, ssrc);

    gemm_rows<384, 8><<<NN / 8, 128, 0, stream>>>(x, W_fc1, nullptr, h1, NN);
    gemm_rows<384, 8><<<NN / 8, 128, 0, stream>>>(x, W_fcv, b_fcv, pv, NN);
    kv_reduce<<<512, 256, 0, stream>>>(h1, pv, kvz);
    attn_apply<<<NN / 8, 128, 0, stream>>>(h1, kvz, att);
    gemm_rows<384, 8><<<NN / 8, 128, 0, stream>>>(att, W_out, nullptr, o, NN);
    vecdot_kernel<<<NN / 8, 128, 0, stream>>>(vec, W_vecproj, pv, vdot, P);
    edge_agg_kernel<<<NN, 256, 0, stream>>>(off, ssrc, se, edge_vec, P, agg);
    outx_kernel<<<NN / 8, 128, 0, stream>>>(att, vdot, o, W_fco, b_fco, h1, edge_weight, out_x);
    outvec_kernel<<<(NN * 3) / 8, 128, 0, stream>>>(vec, W_vecproj, o, agg, ln_scale, ln_bias,
                                                    W_equiv, out_vec);
}

// Round 4
// 685.304 us; speedup vs baseline: 1.7986x; 1.3436x over previous
//
#include <hip/hip_runtime.h>
#include <math.h>

#define NN 30000
#define EE 480000
#define DIM 128

typedef __attribute__((ext_vector_type(8))) short bf16x8;
typedef __attribute__((ext_vector_type(4))) float f32x4;
typedef __attribute__((ext_vector_type(4))) float float4v;

__device__ inline short f2bf(float f) {      // RNE f32 -> bf16
    union { float f; unsigned u; } v; v.f = f;
    unsigned u = v.u;
    u += 0x7fffu + ((u >> 16) & 1u);
    return (short)(u >> 16);
}

__device__ inline bf16x8 cvt8(float4v lo, float4v hi) {
    bf16x8 r;
    r[0] = f2bf(lo[0]); r[1] = f2bf(lo[1]); r[2] = f2bf(lo[2]); r[3] = f2bf(lo[3]);
    r[4] = f2bf(hi[0]); r[5] = f2bf(hi[1]); r[6] = f2bf(hi[2]); r[7] = f2bf(hi[3]);
    return r;
}

// ---------------- weight pre-pack: W (K=128 x Nsrc f32, col range c0..c0+NC) ->
// fragment-major bf16: Wpk[(fid*64+lane)*8+i] = W[kk*32+(lane>>4)*8+i][c0+ct*16+(lane&15)]
// fid global over all weights; frag counts: fc1 96, fcv 96, wout 96, wvp12 64, wvp3 32, fco 32, weq 32
__global__ void pack_all(const float* __restrict__ fc1, const float* __restrict__ fcv,
                         const float* __restrict__ wout, const float* __restrict__ wvp,
                         const float* __restrict__ fco, const float* __restrict__ weq,
                         short* __restrict__ Wpk) {
    int fid = blockIdx.x * 4 + (threadIdx.x >> 6);
    int lane = threadIdx.x & 63;
    const float* src; int Nsrc, c0, f;
    if (fid < 96)       { src = fc1;  Nsrc = 384; c0 = 0;   f = fid; }
    else if (fid < 192) { src = fcv;  Nsrc = 384; c0 = 0;   f = fid - 96; }
    else if (fid < 288) { src = wout; Nsrc = 384; c0 = 0;   f = fid - 192; }
    else if (fid < 352) { src = wvp;  Nsrc = 384; c0 = 0;   f = fid - 288; }
    else if (fid < 384) { src = wvp;  Nsrc = 384; c0 = 256; f = fid - 352; }
    else if (fid < 416) { src = fco;  Nsrc = 128; c0 = 0;   f = fid - 384; }
    else                { src = weq;  Nsrc = 128; c0 = 0;   f = fid - 416; }
    int ct = f >> 2, kk = f & 3;
    int k0 = kk * 32 + (lane >> 4) * 8;
    int col = c0 + ct * 16 + (lane & 15);
    bf16x8 v;
#pragma unroll
    for (int i = 0; i < 8; ++i) v[i] = f2bf(src[(size_t)(k0 + i) * Nsrc + col]);
    *(bf16x8*)(Wpk + ((size_t)fid * 64 + lane) * 8) = v;
}

// ---------------- generic MFMA GEMM: out[n, :COLS] = in[n, :128] @ W (+bias) --------------
// 4 waves/block, 32 rows/wave, A-frags from global f32 (cvt), B-frags from packed bf16.
template<int COLS, bool BIAS>
__global__ __launch_bounds__(256) void mfma_gemm(const float* __restrict__ in,
        const short* __restrict__ Wpk, const float* __restrict__ bias,
        float* __restrict__ out, int nrows) {
    const int lane = threadIdx.x & 63;
    const int wid = threadIdx.x >> 6;
    const int rbase = blockIdx.x * 128 + wid * 32;
    if (rbase >= nrows) return;
    const int rlo = lane & 15, khi = (lane >> 4) * 8;
    bf16x8 a[2][4];
#pragma unroll
    for (int t = 0; t < 2; ++t) {
        int row = min(rbase + t * 16 + rlo, nrows - 1);
        const float* rp = in + (size_t)row * 128 + khi;
#pragma unroll
        for (int kk = 0; kk < 4; ++kk) {
            float4v lo = *(const float4v*)(rp + kk * 32);
            float4v hi = *(const float4v*)(rp + kk * 32 + 4);
            a[t][kk] = cvt8(lo, hi);
        }
    }
    for (int ct = 0; ct < COLS / 16; ++ct) {
        bf16x8 b[4];
#pragma unroll
        for (int kk = 0; kk < 4; ++kk)
            b[kk] = *(const bf16x8*)(Wpk + ((size_t)(ct * 4 + kk) * 64 + lane) * 8);
        f32x4 acc0 = {0.f, 0.f, 0.f, 0.f}, acc1 = {0.f, 0.f, 0.f, 0.f};
#pragma unroll
        for (int kk = 0; kk < 4; ++kk) {
            acc0 = __builtin_amdgcn_mfma_f32_16x16x32_bf16(a[0][kk], b[kk], acc0, 0, 0, 0);
            acc1 = __builtin_amdgcn_mfma_f32_16x16x32_bf16(a[1][kk], b[kk], acc1, 0, 0, 0);
        }
        const int col = ct * 16 + rlo;
        const float bv = BIAS ? bias[col] : 0.f;
#pragma unroll
        for (int r = 0; r < 4; ++r) {
            int row0 = rbase + (lane >> 4) * 4 + r;
            if (row0 < nrows) out[(size_t)row0 * COLS + col] = acc0[r] + bv;
            int row1 = row0 + 16;
            if (row1 < nrows) out[(size_t)row1 * COLS + col] = acc1[r] + bv;
        }
    }
}

// ---------------- kv[h][f][d] = sum_n phi(k)*v; z = sum_n phi(k) ----------------
__global__ void kv_reduce(const float* __restrict__ h1, const float* __restrict__ pv,
                          float* __restrict__ kvz) {
    __shared__ float kf_s[8][DIM];
    __shared__ float v_s[8][DIM];
    const int tid = threadIdx.x;              // 256
    float acc[8];
#pragma unroll
    for (int i = 0; i < 8; ++i) acc[i] = 0.f;
    float zacc = 0.f;
    const int rpb = (NN + gridDim.x - 1) / gridDim.x;
    const int n0 = blockIdx.x * rpb;
    const int n1 = min(n0 + rpb, NN);
    const int base = tid * 8;
    const int hf = base >> 4;
    const int h = hf >> 4;
    const int d0 = base & 15;
    for (int nt = n0; nt < n1; nt += 8) {
        const int m = min(8, n1 - nt);
#pragma unroll
        for (int r = 0; r < 8; ++r) {
            if (r < m) {
                int n = nt + r;
                if (tid < 128) {
                    float kv = h1[(size_t)n * 384 + 128 + tid];
                    kf_s[r][tid] = kv > 0.f ? kv + 1.f : expf(kv);
                } else {
                    v_s[r][tid - 128] = pv[(size_t)n * 384 + (tid - 128)];
                }
            } else {
                if (tid < 128) kf_s[r][tid] = 0.f; else v_s[r][tid - 128] = 0.f;
            }
        }
        __syncthreads();
#pragma unroll
        for (int r = 0; r < 8; ++r) {
            float kfv = kf_s[r][hf];
#pragma unroll
            for (int i = 0; i < 8; ++i) acc[i] = fmaf(kfv, v_s[r][h * 16 + d0 + i], acc[i]);
            if (tid < 128) zacc += kf_s[r][tid];
        }
        __syncthreads();
    }
#pragma unroll
    for (int i = 0; i < 8; ++i) atomicAdd(&kvz[base + i], acc[i]);
    if (tid < 128) atomicAdd(&kvz[2048 + tid], zacc);
}

// ---------------- att[n,h*16+d] = (qf . kv) / (qf . z + 1e-6), 8 rows per block ------------
__global__ void attn_apply(const float* __restrict__ h1, const float* __restrict__ kvz,
                           float* __restrict__ att) {
    __shared__ float kv_s[8 * 16 * 17];
    __shared__ float z_s[DIM];
    __shared__ float qf_s[8][DIM];
    const int tid = threadIdx.x;              // 128
    const int n0 = blockIdx.x * 8;
    for (int i = tid; i < 2048; i += 128) {
        int hf = i >> 4, d = i & 15;
        kv_s[hf * 17 + d] = kvz[i];
    }
    z_s[tid] = kvz[2048 + tid];
#pragma unroll
    for (int r = 0; r < 8; ++r) {
        float qv = h1[(size_t)(n0 + r) * 384 + tid];
        qf_s[r][tid] = qv > 0.f ? qv + 1.f : expf(qv);
    }
    __syncthreads();
    const int h = tid >> 4, d = tid & 15;
#pragma unroll
    for (int r = 0; r < 8; ++r) {
        float num = 0.f, den = 0.f;
#pragma unroll
        for (int f = 0; f < 16; ++f) {
            float q = qf_s[r][h * 16 + f];
            num = fmaf(q, kv_s[(h * 16 + f) * 17 + d], num);
            den = fmaf(q, z_s[h * 16 + f], den);
        }
        att[(size_t)(n0 + r) * DIM + tid] = num / (den + 1e-6f);
    }
}

// ---------------- vdot + P-pack from vp12 (90000x256: v1p|v2p) ----------------
__global__ void vecdot_reduce(const float* __restrict__ vp12, const float* __restrict__ vec,
                              const float* __restrict__ pv, float* __restrict__ vdot,
                              float* __restrict__ P) {
    const int tid = threadIdx.x;              // 128
    const int n0 = blockIdx.x * 8;
#pragma unroll
    for (int r = 0; r < 8; ++r) {
        int n = n0 + r;
        const float* vp = vp12 + (size_t)(3 * n) * 256;
        float acc = vp[tid] * vp[128 + tid]
                  + vp[256 + tid] * vp[384 + tid]
                  + vp[512 + tid] * vp[640 + tid];
        vdot[(size_t)n * DIM + tid] = acc;
        float v1 = pv[(size_t)n * 384 + 128 + tid];
        float v2 = pv[(size_t)n * 384 + 256 + tid];
        float* pr = P + (size_t)n * 512;
        pr[tid]       = v2;
        pr[128 + tid] = vec[((size_t)n * 3 + 0) * DIM + tid] * v1;
        pr[256 + tid] = vec[((size_t)n * 3 + 1) * DIM + tid] * v1;
        pr[384 + tid] = vec[((size_t)n * 3 + 2) * DIM + tid] * v1;
    }
}

// ---------------- edge CSR build ----------------
__global__ void hist_kernel(const int* __restrict__ eidx, int* __restrict__ cnt) {
    int e = blockIdx.x * 256 + threadIdx.x;
    if (e < EE) atomicAdd(&cnt[eidx[EE + e]], 1);
}

__global__ void scan_kernel(const int* __restrict__ cnt, int* __restrict__ off,
                            int* __restrict__ pos) {
    __shared__ int tsum[1024];
    const int tid = threadIdx.x;              // 1024
    const int PER = 30;
    const int base = tid * PER;
    int local[PER];
    int s = 0;
#pragma unroll
    for (int i = 0; i < PER; ++i) {
        int idx = base + i;
        int c = (idx < NN) ? cnt[idx] : 0;
        local[i] = s;
        s += c;
    }
    tsum[tid] = s;
    __syncthreads();
    for (int d = 1; d < 1024; d <<= 1) {
        int v = (tid >= d) ? tsum[tid - d] : 0;
        __syncthreads();
        tsum[tid] += v;
        __syncthreads();
    }
    const int carry = (tid == 0) ? 0 : tsum[tid - 1];
#pragma unroll
    for (int i = 0; i < PER; ++i) {
        int idx = base + i;
        if (idx < NN) {
            int v = carry + local[i];
            off[idx] = v;
            pos[idx] = v;
        }
    }
    if (tid == 1023) off[NN] = tsum[1023];
}

__global__ void scatter_kernel(const int* __restrict__ eidx, int* __restrict__ pos,
                               int* __restrict__ se, int* __restrict__ ssrc) {
    int e = blockIdx.x * 256 + threadIdx.x;
    if (e >= EE) return;
    int dst = eidx[EE + e];
    int p = atomicAdd(&pos[dst], 1);
    se[p] = e;
    ssrc[p] = eidx[e];
}

// ---------------- segmented gather-reduce: one block (2 groups) per dst --------------------
__global__ __launch_bounds__(256) void edge_agg_kernel(
        const int* __restrict__ off, const int* __restrict__ ssrc,
        const int* __restrict__ se, const float* __restrict__ evec,
        const float* __restrict__ P, float* __restrict__ agg) {
    __shared__ int srcs[128];
    __shared__ float evs[3][128];
    __shared__ float part[3][128];
    const int dst = blockIdx.x;
    const int tid = threadIdx.x;              // 256
    const int g = tid >> 7, o = tid & 127;
    const int j0 = off[dst], j1 = off[dst + 1];
    float a0 = 0.f, a1 = 0.f, a2 = 0.f;
    for (int jt = j0; jt < j1; jt += 128) {
        const int m = min(128, j1 - jt);
        if (tid < m) {
            srcs[tid] = ssrc[jt + tid];
            int e = se[jt + tid];
            evs[0][tid] = evec[(size_t)e * 3 + 0];
            evs[1][tid] = evec[(size_t)e * 3 + 1];
            evs[2][tid] = evec[(size_t)e * 3 + 2];
        }
        __syncthreads();
        for (int jj = g; jj < m; jj += 2) {
            const float* p = P + (size_t)srcs[jj] * 512;
            float b = p[o];
            a0 += fmaf(evs[0][jj], b, p[128 + o]);
            a1 += fmaf(evs[1][jj], b, p[256 + o]);
            a2 += fmaf(evs[2][jj], b, p[384 + o]);
        }
        __syncthreads();
    }
    if (g == 1) { part[0][o] = a0; part[1][o] = a1; part[2][o] = a2; }
    __syncthreads();
    if (g == 0) {
        a0 += part[0][o]; a1 += part[1][o]; a2 += part[2][o];
        agg[((size_t)dst * 3 + 0) * DIM + o] = a0;
        agg[((size_t)dst * 3 + 1) * DIM + o] = a1;
        agg[((size_t)dst * 3 + 2) * DIM + o] = a2;
    }
}

// ---------------- out_x = non_att + ((att + vdot*o2 + o3) @ W_fco + b_fco)*ew (MFMA) ------
__global__ __launch_bounds__(256) void outx_mfma(const float* __restrict__ att,
        const float* __restrict__ vdot, const float* __restrict__ o,
        const short* __restrict__ Wpk, const float* __restrict__ bfco,
        const float* __restrict__ h1, const float* __restrict__ ew,
        float* __restrict__ outx) {
    const int lane = threadIdx.x & 63;
    const int wid = threadIdx.x >> 6;
    const int rbase = blockIdx.x * 128 + wid * 32;
    if (rbase >= NN) return;
    const int rlo = lane & 15, khi = (lane >> 4) * 8;
    bf16x8 a[2][4];
#pragma unroll
    for (int t = 0; t < 2; ++t) {
        int row = min(rbase + t * 16 + rlo, NN - 1);
        const float* pa = att + (size_t)row * 128 + khi;
        const float* pd = vdot + (size_t)row * 128 + khi;
        const float* po = o + (size_t)row * 384 + khi;
#pragma unroll
        for (int kk = 0; kk < 4; ++kk) {
            int kb = kk * 32;
            float4v al = *(const float4v*)(pa + kb), ah = *(const float4v*)(pa + kb + 4);
            float4v dl = *(const float4v*)(pd + kb), dh = *(const float4v*)(pd + kb + 4);
            float4v o2l = *(const float4v*)(po + kb + 128), o2h = *(const float4v*)(po + kb + 132);
            float4v o3l = *(const float4v*)(po + kb + 256), o3h = *(const float4v*)(po + kb + 260);
            a[t][kk] = cvt8(al + dl * o2l + o3l, ah + dh * o2h + o3h);
        }
    }
    float ewv[2][4];
#pragma unroll
    for (int t = 0; t < 2; ++t)
#pragma unroll
        for (int r = 0; r < 4; ++r)
            ewv[t][r] = ew[min(rbase + t * 16 + (lane >> 4) * 4 + r, NN - 1)];
    for (int ct = 0; ct < 8; ++ct) {
        bf16x8 b[4];
#pragma unroll
        for (int kk = 0; kk < 4; ++kk)
            b[kk] = *(const bf16x8*)(Wpk + ((size_t)(ct * 4 + kk) * 64 + lane) * 8);
        f32x4 acc0 = {0.f, 0.f, 0.f, 0.f}, acc1 = {0.f, 0.f, 0.f, 0.f};
#pragma unroll
        for (int kk = 0; kk < 4; ++kk) {
            acc0 = __builtin_amdgcn_mfma_f32_16x16x32_bf16(a[0][kk], b[kk], acc0, 0, 0, 0);
            acc1 = __builtin_amdgcn_mfma_f32_16x16x32_bf16(a[1][kk], b[kk], acc1, 0, 0, 0);
        }
        const int col = ct * 16 + rlo;
        const float bv = bfco[col];
#pragma unroll
        for (int r = 0; r < 4; ++r) {
            int row0 = rbase + (lane >> 4) * 4 + r;
            if (row0 < NN)
                outx[(size_t)row0 * 128 + col] =
                    h1[(size_t)row0 * 384 + 256 + col] + (acc0[r] + bv) * ewv[0][r];
            int row1 = row0 + 16;
            if (row1 < NN)
                outx[(size_t)row1 * 128 + col] =
                    h1[(size_t)row1 * 384 + 256 + col] + (acc1[r] + bv) * ewv[1][r];
        }
    }
}

// ---------------- outvec part1: dvn = LN(v3p*o1 + agg)  (MFMA v3 GEMM + in-reg LN) --------
__global__ __launch_bounds__(256) void outvec1(const float* __restrict__ vec,
        const short* __restrict__ Wpk3, const float* __restrict__ o,
        const float* __restrict__ agg, const float* __restrict__ ln_scale,
        const float* __restrict__ ln_bias, float* __restrict__ dvn) {
    const int NR = 3 * NN;
    const int lane = threadIdx.x & 63;
    const int wid = threadIdx.x >> 6;
    const int rbase = blockIdx.x * 128 + wid * 32;
    if (rbase >= NR) return;
    const int rlo = lane & 15, khi = (lane >> 4) * 8;
    bf16x8 a[2][4];
#pragma unroll
    for (int t = 0; t < 2; ++t) {
        int row = min(rbase + t * 16 + rlo, NR - 1);
        const float* rp = vec + (size_t)row * 128 + khi;
#pragma unroll
        for (int kk = 0; kk < 4; ++kk) {
            float4v lo = *(const float4v*)(rp + kk * 32);
            float4v hi = *(const float4v*)(rp + kk * 32 + 4);
            a[t][kk] = cvt8(lo, hi);
        }
    }
    f32x4 acc[2][8];
#pragma unroll
    for (int ct = 0; ct < 8; ++ct) {
        bf16x8 b[4];
#pragma unroll
        for (int kk = 0; kk < 4; ++kk)
            b[kk] = *(const bf16x8*)(Wpk3 + ((size_t)(ct * 4 + kk) * 64 + lane) * 8);
        f32x4 a0 = {0.f, 0.f, 0.f, 0.f}, a1 = {0.f, 0.f, 0.f, 0.f};
#pragma unroll
        for (int kk = 0; kk < 4; ++kk) {
            a0 = __builtin_amdgcn_mfma_f32_16x16x32_bf16(a[0][kk], b[kk], a0, 0, 0, 0);
            a1 = __builtin_amdgcn_mfma_f32_16x16x32_bf16(a[1][kk], b[kk], a1, 0, 0, 0);
        }
        acc[0][ct] = a0; acc[1][ct] = a1;
    }
    // dvs = v3*o1 + agg; accumulate LN stats per row
    float s[2][4], s2[2][4];
#pragma unroll
    for (int t = 0; t < 2; ++t)
#pragma unroll
        for (int r = 0; r < 4; ++r) { s[t][r] = 0.f; s2[t][r] = 0.f; }
#pragma unroll
    for (int t = 0; t < 2; ++t)
#pragma unroll
        for (int r = 0; r < 4; ++r) {
            int row = min(rbase + t * 16 + (lane >> 4) * 4 + r, NR - 1);
            int n = row / 3;
#pragma unroll
            for (int ct = 0; ct < 8; ++ct) {
                int col = ct * 16 + rlo;
                float dv = acc[t][ct][r] * o[(size_t)n * 384 + col]
                         + agg[(size_t)row * 128 + col];
                acc[t][ct][r] = dv;
                s[t][r] += dv;
                s2[t][r] = fmaf(dv, dv, s2[t][r]);
            }
        }
#pragma unroll
    for (int t = 0; t < 2; ++t)
#pragma unroll
        for (int r = 0; r < 4; ++r) {
#pragma unroll
            for (int m = 1; m < 16; m <<= 1) {
                s[t][r] += __shfl_xor(s[t][r], m, 16);
                s2[t][r] += __shfl_xor(s2[t][r], m, 16);
            }
        }
#pragma unroll
    for (int t = 0; t < 2; ++t)
#pragma unroll
        for (int r = 0; r < 4; ++r) {
            int row = rbase + t * 16 + (lane >> 4) * 4 + r;
            if (row >= NR) continue;
            float mu = s[t][r] * (1.f / 128.f);
            float rstd = rsqrtf(s2[t][r] * (1.f / 128.f) - mu * mu + 1e-5f);
#pragma unroll
            for (int ct = 0; ct < 8; ++ct) {
                int col = ct * 16 + rlo;
                dvn[(size_t)row * 128 + col] =
                    fmaf((acc[t][ct][r] - mu) * rstd, ln_scale[col], ln_bias[col]);
            }
        }
}

extern "C" void kernel_launch(void* const* d_in, const int* in_sizes, int n_in,
                              void* d_out, int out_size, void* d_ws, size_t ws_size,
                              hipStream_t stream) {
    const float* x          = (const float*)d_in[0];
    const float* vec        = (const float*)d_in[1];
    const float* edge_vec   = (const float*)d_in[2];
    const float* edge_weight= (const float*)d_in[3];
    const float* W_fc1      = (const float*)d_in[4];
    const float* W_fcv      = (const float*)d_in[5];
    const float* b_fcv      = (const float*)d_in[6];
    const float* W_fco      = (const float*)d_in[7];
    const float* b_fco      = (const float*)d_in[8];
    const float* W_out      = (const float*)d_in[9];
    const float* W_vecproj  = (const float*)d_in[10];
    const float* W_equiv    = (const float*)d_in[11];
    const float* ln_scale   = (const float*)d_in[12];
    const float* ln_bias    = (const float*)d_in[13];
    const int*   edge_index = (const int*)d_in[14];

    float* out_x   = (float*)d_out;
    float* out_vec = out_x + (size_t)NN * DIM;
    float* P       = (float*)d_out;           // N x 512, alias (dead before out writes)

    float* ws   = (float*)d_ws;
    float* h1   = ws;                          // N*384
    float* pv   = h1 + 11520000;               // N*384
    float* att  = pv + 11520000;               // N*128
    float* vdot = att + 3840000;               // N*128
    float* o    = vdot + 3840000;              // N*384
    float* agg  = o + 11520000;                // 3N*128  (o..agg contiguous: vp12 alias)
    float* kvz  = agg + 11520000;              // 2176
    float* vp12 = o;                           // 3N*256 = o + agg slots, consumed before both
    float* dvn  = pv;                          // 3N*128 reuses dead pv slot
    int* cnt    = (int*)(kvz + 2176);          // N
    int* off    = cnt + NN;                    // N+1
    int* pos    = off + NN + 1;                // N
    int* se     = pos + NN;                    // E
    int* ssrc   = se + EE;                     // E
    size_t woff = ((size_t)(ssrc + EE - (int*)ws) + 3) & ~(size_t)3;   // 16B align
    short* Wpk  = (short*)(ws + woff);         // 448 frags * 512 shorts
    short* pk_fc1  = Wpk;
    short* pk_fcv  = Wpk + 96 * 512;
    short* pk_wout = Wpk + 192 * 512;
    short* pk_vp12 = Wpk + 288 * 512;
    short* pk_vp3  = Wpk + 352 * 512;
    short* pk_fco  = Wpk + 384 * 512;
    short* pk_weq  = Wpk + 416 * 512;

    hipMemsetAsync(kvz, 0, 2176 * sizeof(float), stream);
    hipMemsetAsync(cnt, 0, NN * sizeof(int), stream);

    pack_all<<<112, 256, 0, stream>>>(W_fc1, W_fcv, W_out, W_vecproj, W_fco, W_equiv, Wpk);

    // CSR build (depends only on edge_index)
    hist_kernel<<<(EE + 255) / 256, 256, 0, stream>>>(edge_index, cnt);
    scan_kernel<<<1, 1024, 0, stream>>>(cnt, off, pos);
    scatter_kernel<<<(EE + 255) / 256, 256, 0, stream>>>(edge_index, pos, se, ssrc);

    const int gN = (NN + 127) / 128;           // 235
    const int g3N = (3 * NN + 127) / 128;      // 704
    mfma_gemm<384, false><<<gN, 256, 0, stream>>>(x, pk_fc1, nullptr, h1, NN);
    mfma_gemm<384, true><<<gN, 256, 0, stream>>>(x, pk_fcv, b_fcv, pv, NN);
    kv_reduce<<<512, 256, 0, stream>>>(h1, pv, kvz);
    attn_apply<<<NN / 8, 128, 0, stream>>>(h1, kvz, att);
    mfma_gemm<256, false><<<g3N, 256, 0, stream>>>(vec, pk_vp12, nullptr, vp12, 3 * NN);
    vecdot_reduce<<<NN / 8, 128, 0, stream>>>(vp12, vec, pv, vdot, P);
    mfma_gemm<384, false><<<gN, 256, 0, stream>>>(att, pk_wout, nullptr, o, NN);
    edge_agg_kernel<<<NN, 256, 0, stream>>>(off, ssrc, se, edge_vec, P, agg);
    outx_mfma<<<gN, 256, 0, stream>>>(att, vdot, o, pk_fco, b_fco, h1, edge_weight, out_x);
    outvec1<<<g3N, 256, 0, stream>>>(vec, pk_vp3, o, agg, ln_scale, ln_bias, dvn);
    mfma_gemm<128, false><<<g3N, 256, 0, stream>>>(dvn, pk_weq, nullptr, out_vec, 3 * NN);
}

// Round 5
// 600.249 us; speedup vs baseline: 2.0534x; 1.1417x over previous
//
#include <hip/hip_runtime.h>
#include <math.h>

#define NN 30000
#define EE 480000
#define DIM 128

typedef __attribute__((ext_vector_type(8))) short bf16x8;
typedef __attribute__((ext_vector_type(4))) short s16x4;
typedef __attribute__((ext_vector_type(4))) float f32x4;
typedef __attribute__((ext_vector_type(4))) float float4v;

__device__ inline short f2bf(float f) {      // RNE f32 -> bf16
    union { float f; unsigned u; } v; v.f = f;
    unsigned u = v.u;
    u += 0x7fffu + ((u >> 16) & 1u);
    return (short)(u >> 16);
}
__device__ inline float bf2f(unsigned short u) {
    union { unsigned u; float f; } v; v.u = ((unsigned)u) << 16; return v.f;
}

__device__ inline bf16x8 cvt8(float4v lo, float4v hi) {
    bf16x8 r;
    r[0] = f2bf(lo[0]); r[1] = f2bf(lo[1]); r[2] = f2bf(lo[2]); r[3] = f2bf(lo[3]);
    r[4] = f2bf(hi[0]); r[5] = f2bf(hi[1]); r[6] = f2bf(hi[2]); r[7] = f2bf(hi[3]);
    return r;
}

// ---------------- weight pre-pack (fragment-major bf16) ----------------
__global__ void pack_all(const float* __restrict__ fc1, const float* __restrict__ fcv,
                         const float* __restrict__ wout, const float* __restrict__ wvp,
                         const float* __restrict__ fco, const float* __restrict__ weq,
                         short* __restrict__ Wpk) {
    int fid = blockIdx.x * 4 + (threadIdx.x >> 6);
    int lane = threadIdx.x & 63;
    const float* src; int Nsrc, c0, f;
    if (fid < 96)       { src = fc1;  Nsrc = 384; c0 = 0;   f = fid; }
    else if (fid < 192) { src = fcv;  Nsrc = 384; c0 = 0;   f = fid - 96; }
    else if (fid < 288) { src = wout; Nsrc = 384; c0 = 0;   f = fid - 192; }
    else if (fid < 352) { src = wvp;  Nsrc = 384; c0 = 0;   f = fid - 288; }
    else if (fid < 384) { src = wvp;  Nsrc = 384; c0 = 256; f = fid - 352; }
    else if (fid < 416) { src = fco;  Nsrc = 128; c0 = 0;   f = fid - 384; }
    else                { src = weq;  Nsrc = 128; c0 = 0;   f = fid - 416; }
    int ct = f >> 2, kk = f & 3;
    int k0 = kk * 32 + (lane >> 4) * 8;
    int col = c0 + ct * 16 + (lane & 15);
    bf16x8 v;
#pragma unroll
    for (int i = 0; i < 8; ++i) v[i] = f2bf(src[(size_t)(k0 + i) * Nsrc + col]);
    *(bf16x8*)(Wpk + ((size_t)fid * 64 + lane) * 8) = v;
}

// ---------------- generic MFMA GEMM: out[n,:COLS] = in[n,:128] @ W (+bias) ----------------
// InT: float (cvt in-flight) or ushort (bf16, direct fragment load).
// OutT: float or ushort (bf16 store).
template<int COLS, bool BIAS, typename InT, typename OutT>
__global__ __launch_bounds__(256) void mfma_gemm(const InT* __restrict__ in,
        const short* __restrict__ Wpk, const float* __restrict__ bias,
        OutT* __restrict__ out, int nrows) {
    const int lane = threadIdx.x & 63;
    const int wid = threadIdx.x >> 6;
    const int rbase = blockIdx.x * 128 + wid * 32;
    if (rbase >= nrows) return;
    const int rlo = lane & 15, khi = (lane >> 4) * 8;
    bf16x8 a[2][4];
#pragma unroll
    for (int t = 0; t < 2; ++t) {
        int row = min(rbase + t * 16 + rlo, nrows - 1);
        const InT* rp = in + (size_t)row * 128 + khi;
#pragma unroll
        for (int kk = 0; kk < 4; ++kk) {
            if constexpr (sizeof(InT) == 4) {
                float4v lo = *(const float4v*)(rp + kk * 32);
                float4v hi = *(const float4v*)(rp + kk * 32 + 4);
                a[t][kk] = cvt8(lo, hi);
            } else {
                a[t][kk] = *(const bf16x8*)(rp + kk * 32);
            }
        }
    }
    for (int ct = 0; ct < COLS / 16; ++ct) {
        bf16x8 b[4];
#pragma unroll
        for (int kk = 0; kk < 4; ++kk)
            b[kk] = *(const bf16x8*)(Wpk + ((size_t)(ct * 4 + kk) * 64 + lane) * 8);
        f32x4 acc0 = {0.f, 0.f, 0.f, 0.f}, acc1 = {0.f, 0.f, 0.f, 0.f};
#pragma unroll
        for (int kk = 0; kk < 4; ++kk) {
            acc0 = __builtin_amdgcn_mfma_f32_16x16x32_bf16(a[0][kk], b[kk], acc0, 0, 0, 0);
            acc1 = __builtin_amdgcn_mfma_f32_16x16x32_bf16(a[1][kk], b[kk], acc1, 0, 0, 0);
        }
        const int col = ct * 16 + rlo;
        const float bv = BIAS ? bias[col] : 0.f;
#pragma unroll
        for (int r = 0; r < 4; ++r) {
            int row0 = rbase + (lane >> 4) * 4 + r;
            int row1 = row0 + 16;
            if constexpr (sizeof(OutT) == 4) {
                if (row0 < nrows) out[(size_t)row0 * COLS + col] = acc0[r] + bv;
                if (row1 < nrows) out[(size_t)row1 * COLS + col] = acc1[r] + bv;
            } else {
                if (row0 < nrows) out[(size_t)row0 * COLS + col] = (OutT)f2bf(acc0[r] + bv);
                if (row1 < nrows) out[(size_t)row1 * COLS + col] = (OutT)f2bf(acc1[r] + bv);
            }
        }
    }
}

// ---------------- kv[h][f][d] = sum_n phi(k)*v; z = sum_n phi(k) ----------------
__global__ void kv_reduce(const float* __restrict__ h1, const float* __restrict__ pv,
                          float* __restrict__ kvz) {
    __shared__ float kf_s[8][DIM];
    __shared__ float v_s[8][DIM];
    const int tid = threadIdx.x;              // 256
    float acc[8];
#pragma unroll
    for (int i = 0; i < 8; ++i) acc[i] = 0.f;
    float zacc = 0.f;
    const int rpb = (NN + gridDim.x - 1) / gridDim.x;
    const int n0 = blockIdx.x * rpb;
    const int n1 = min(n0 + rpb, NN);
    const int base = tid * 8;
    const int hf = base >> 4;
    const int h = hf >> 4;
    const int d0 = base & 15;
    for (int nt = n0; nt < n1; nt += 8) {
        const int m = min(8, n1 - nt);
#pragma unroll
        for (int r = 0; r < 8; ++r) {
            if (r < m) {
                int n = nt + r;
                if (tid < 128) {
                    float kv = h1[(size_t)n * 384 + 128 + tid];
                    kf_s[r][tid] = kv > 0.f ? kv + 1.f : expf(kv);
                } else {
                    v_s[r][tid - 128] = pv[(size_t)n * 384 + (tid - 128)];
                }
            } else {
                if (tid < 128) kf_s[r][tid] = 0.f; else v_s[r][tid - 128] = 0.f;
            }
        }
        __syncthreads();
#pragma unroll
        for (int r = 0; r < 8; ++r) {
            float kfv = kf_s[r][hf];
#pragma unroll
            for (int i = 0; i < 8; ++i) acc[i] = fmaf(kfv, v_s[r][h * 16 + d0 + i], acc[i]);
            if (tid < 128) zacc += kf_s[r][tid];
        }
        __syncthreads();
    }
#pragma unroll
    for (int i = 0; i < 8; ++i) atomicAdd(&kvz[base + i], acc[i]);
    if (tid < 128) atomicAdd(&kvz[2048 + tid], zacc);
}

// ---------------- att[n,h*16+d] = (qf . kv) / (qf . z + 1e-6), 8 rows per block ------------
__global__ void attn_apply(const float* __restrict__ h1, const float* __restrict__ kvz,
                           float* __restrict__ att) {
    __shared__ float kv_s[8 * 16 * 17];
    __shared__ float z_s[DIM];
    __shared__ float qf_s[8][DIM];
    const int tid = threadIdx.x;              // 128
    const int n0 = blockIdx.x * 8;
    for (int i = tid; i < 2048; i += 128) {
        int hf = i >> 4, d = i & 15;
        kv_s[hf * 17 + d] = kvz[i];
    }
    z_s[tid] = kvz[2048 + tid];
#pragma unroll
    for (int r = 0; r < 8; ++r) {
        float qv = h1[(size_t)(n0 + r) * 384 + tid];
        qf_s[r][tid] = qv > 0.f ? qv + 1.f : expf(qv);
    }
    __syncthreads();
    const int h = tid >> 4, d = tid & 15;
#pragma unroll
    for (int r = 0; r < 8; ++r) {
        float num = 0.f, den = 0.f;
#pragma unroll
        for (int f = 0; f < 16; ++f) {
            float q = qf_s[r][h * 16 + f];
            num = fmaf(q, kv_s[(h * 16 + f) * 17 + d], num);
            den = fmaf(q, z_s[h * 16 + f], den);
        }
        att[(size_t)(n0 + r) * DIM + tid] = num / (den + 1e-6f);
    }
}

// ---------------- vdot + bf16 P-pack (interleaved layout: P[n][o*4 + {v2,m0,m1,m2}]) ------
__global__ void vecdot_reduce(const unsigned short* __restrict__ vp12,
                              const float* __restrict__ vec, const float* __restrict__ pv,
                              float* __restrict__ vdot, unsigned short* __restrict__ P) {
    const int tid = threadIdx.x;              // 128
    const int n0 = blockIdx.x * 8;
#pragma unroll
    for (int r = 0; r < 8; ++r) {
        int n = n0 + r;
        const unsigned short* vp = vp12 + (size_t)(3 * n) * 256;
        float acc = bf2f(vp[tid]) * bf2f(vp[128 + tid])
                  + bf2f(vp[256 + tid]) * bf2f(vp[384 + tid])
                  + bf2f(vp[512 + tid]) * bf2f(vp[640 + tid]);
        vdot[(size_t)n * DIM + tid] = acc;
        float v1 = pv[(size_t)n * 384 + 128 + tid];
        float v2 = pv[(size_t)n * 384 + 256 + tid];
        s16x4 pk;
        pk[0] = f2bf(v2);
        pk[1] = f2bf(vec[((size_t)n * 3 + 0) * DIM + tid] * v1);
        pk[2] = f2bf(vec[((size_t)n * 3 + 1) * DIM + tid] * v1);
        pk[3] = f2bf(vec[((size_t)n * 3 + 2) * DIM + tid] * v1);
        *(s16x4*)(P + (size_t)n * 512 + tid * 4) = pk;
    }
}

// ---------------- edge CSR build ----------------
__global__ void hist_kernel(const int* __restrict__ eidx, int* __restrict__ cnt) {
    int e = blockIdx.x * 256 + threadIdx.x;
    if (e < EE) atomicAdd(&cnt[eidx[EE + e]], 1);
}

__global__ void scan_kernel(const int* __restrict__ cnt, int* __restrict__ off,
                            int* __restrict__ pos) {
    __shared__ int wsum[16];
    const int tid = threadIdx.x;              // 1024
    const int lane = tid & 63, wv = tid >> 6;
    const int PER = 30;
    const int base = tid * PER;
    int local[PER];
    int s = 0;
#pragma unroll
    for (int i = 0; i < PER; ++i) {
        int idx = base + i;
        int c = (idx < NN) ? cnt[idx] : 0;
        local[i] = s;
        s += c;
    }
    int incl = s;                              // wave-inclusive scan of thread sums
#pragma unroll
    for (int d = 1; d < 64; d <<= 1) {
        int v = __shfl_up(incl, d, 64);
        if (lane >= d) incl += v;
    }
    if (lane == 63) wsum[wv] = incl;
    __syncthreads();
    if (wv == 0 && lane < 16) {
        int v = wsum[lane];
        int iv = v;
#pragma unroll
        for (int d = 1; d < 16; d <<= 1) {
            int u = __shfl_up(iv, d, 16);
            if (lane >= d) iv += u;
        }
        wsum[lane] = iv - v;                   // exclusive wave prefix
    }
    __syncthreads();
    const int carry = wsum[wv] + (incl - s);   // exclusive prefix for this thread
#pragma unroll
    for (int i = 0; i < PER; ++i) {
        int idx = base + i;
        if (idx < NN) {
            int v = carry + local[i];
            off[idx] = v;
            pos[idx] = v;
        }
    }
    if (tid == 1023) off[NN] = wsum[15] + incl;
}

__global__ void scatter_kernel(const int* __restrict__ eidx, int* __restrict__ pos,
                               int* __restrict__ se, int* __restrict__ ssrc) {
    int e = blockIdx.x * 256 + threadIdx.x;
    if (e >= EE) return;
    int dst = eidx[EE + e];
    int p = atomicAdd(&pos[dst], 1);
    se[p] = e;
    ssrc[p] = eidx[e];
}

// ---------------- segmented gather-reduce: one block (2 groups) per dst --------------------
// P row = 512 bf16 interleaved; lane o loads one aligned 8B short4.
__global__ __launch_bounds__(256) void edge_agg_kernel(
        const int* __restrict__ off, const int* __restrict__ ssrc,
        const int* __restrict__ se, const float* __restrict__ evec,
        const unsigned short* __restrict__ P, float* __restrict__ agg) {
    __shared__ int srcs[128];
    __shared__ float evs[3][128];
    __shared__ float part[3][128];
    const int dst = blockIdx.x;
    const int tid = threadIdx.x;              // 256
    const int g = tid >> 7, o = tid & 127;
    const int j0 = off[dst], j1 = off[dst + 1];
    float a0 = 0.f, a1 = 0.f, a2 = 0.f;
    for (int jt = j0; jt < j1; jt += 128) {
        const int m = min(128, j1 - jt);
        if (tid < m) {
            srcs[tid] = ssrc[jt + tid];
            int e = se[jt + tid];
            evs[0][tid] = evec[(size_t)e * 3 + 0];
            evs[1][tid] = evec[(size_t)e * 3 + 1];
            evs[2][tid] = evec[(size_t)e * 3 + 2];
        }
        __syncthreads();
        for (int jj = g; jj < m; jj += 2) {
            s16x4 pk = *(const s16x4*)(P + (size_t)srcs[jj] * 512 + o * 4);
            float v2 = bf2f((unsigned short)pk[0]);
            a0 += fmaf(evs[0][jj], v2, bf2f((unsigned short)pk[1]));
            a1 += fmaf(evs[1][jj], v2, bf2f((unsigned short)pk[2]));
            a2 += fmaf(evs[2][jj], v2, bf2f((unsigned short)pk[3]));
        }
        __syncthreads();
    }
    if (g == 1) { part[0][o] = a0; part[1][o] = a1; part[2][o] = a2; }
    __syncthreads();
    if (g == 0) {
        a0 += part[0][o]; a1 += part[1][o]; a2 += part[2][o];
        agg[((size_t)dst * 3 + 0) * DIM + o] = a0;
        agg[((size_t)dst * 3 + 1) * DIM + o] = a1;
        agg[((size_t)dst * 3 + 2) * DIM + o] = a2;
    }
}

// ---------------- out_x = non_att + ((att + vdot*o2 + o3) @ W_fco + b_fco)*ew (MFMA) ------
__global__ __launch_bounds__(256) void outx_mfma(const float* __restrict__ att,
        const float* __restrict__ vdot, const float* __restrict__ o,
        const short* __restrict__ Wpk, const float* __restrict__ bfco,
        const float* __restrict__ h1, const float* __restrict__ ew,
        float* __restrict__ outx) {
    const int lane = threadIdx.x & 63;
    const int wid = threadIdx.x >> 6;
    const int rbase = blockIdx.x * 128 + wid * 32;
    if (rbase >= NN) return;
    const int rlo = lane & 15, khi = (lane >> 4) * 8;
    bf16x8 a[2][4];
#pragma unroll
    for (int t = 0; t < 2; ++t) {
        int row = min(rbase + t * 16 + rlo, NN - 1);
        const float* pa = att + (size_t)row * 128 + khi;
        const float* pd = vdot + (size_t)row * 128 + khi;
        const float* po = o + (size_t)row * 384 + khi;
#pragma unroll
        for (int kk = 0; kk < 4; ++kk) {
            int kb = kk * 32;
            float4v al = *(const float4v*)(pa + kb), ah = *(const float4v*)(pa + kb + 4);
            float4v dl = *(const float4v*)(pd + kb), dh = *(const float4v*)(pd + kb + 4);
            float4v o2l = *(const float4v*)(po + kb + 128), o2h = *(const float4v*)(po + kb + 132);
            float4v o3l = *(const float4v*)(po + kb + 256), o3h = *(const float4v*)(po + kb + 260);
            a[t][kk] = cvt8(al + dl * o2l + o3l, ah + dh * o2h + o3h);
        }
    }
    float ewv[2][4];
#pragma unroll
    for (int t = 0; t < 2; ++t)
#pragma unroll
        for (int r = 0; r < 4; ++r)
            ewv[t][r] = ew[min(rbase + t * 16 + (lane >> 4) * 4 + r, NN - 1)];
    for (int ct = 0; ct < 8; ++ct) {
        bf16x8 b[4];
#pragma unroll
        for (int kk = 0; kk < 4; ++kk)
            b[kk] = *(const bf16x8*)(Wpk + ((size_t)(ct * 4 + kk) * 64 + lane) * 8);
        f32x4 acc0 = {0.f, 0.f, 0.f, 0.f}, acc1 = {0.f, 0.f, 0.f, 0.f};
#pragma unroll
        for (int kk = 0; kk < 4; ++kk) {
            acc0 = __builtin_amdgcn_mfma_f32_16x16x32_bf16(a[0][kk], b[kk], acc0, 0, 0, 0);
            acc1 = __builtin_amdgcn_mfma_f32_16x16x32_bf16(a[1][kk], b[kk], acc1, 0, 0, 0);
        }
        const int col = ct * 16 + rlo;
        const float bv = bfco[col];
#pragma unroll
        for (int r = 0; r < 4; ++r) {
            int row0 = rbase + (lane >> 4) * 4 + r;
            if (row0 < NN)
                outx[(size_t)row0 * 128 + col] =
                    h1[(size_t)row0 * 384 + 256 + col] + (acc0[r] + bv) * ewv[0][r];
            int row1 = row0 + 16;
            if (row1 < NN)
                outx[(size_t)row1 * 128 + col] =
                    h1[(size_t)row1 * 384 + 256 + col] + (acc1[r] + bv) * ewv[1][r];
        }
    }
}

// ---------------- outvec part1: dvn(bf16) = LN(v3p*o1 + agg) ----------------
__global__ __launch_bounds__(256) void outvec1(const float* __restrict__ vec,
        const short* __restrict__ Wpk3, const float* __restrict__ o,
        const float* __restrict__ agg, const float* __restrict__ ln_scale,
        const float* __restrict__ ln_bias, unsigned short* __restrict__ dvn) {
    const int NR = 3 * NN;
    const int lane = threadIdx.x & 63;
    const int wid = threadIdx.x >> 6;
    const int rbase = blockIdx.x * 128 + wid * 32;
    if (rbase >= NR) return;
    const int rlo = lane & 15, khi = (lane >> 4) * 8;
    bf16x8 a[2][4];
#pragma unroll
    for (int t = 0; t < 2; ++t) {
        int row = min(rbase + t * 16 + rlo, NR - 1);
        const float* rp = vec + (size_t)row * 128 + khi;
#pragma unroll
        for (int kk = 0; kk < 4; ++kk) {
            float4v lo = *(const float4v*)(rp + kk * 32);
            float4v hi = *(const float4v*)(rp + kk * 32 + 4);
            a[t][kk] = cvt8(lo, hi);
        }
    }
    f32x4 acc[2][8];
#pragma unroll
    for (int ct = 0; ct < 8; ++ct) {
        bf16x8 b[4];
#pragma unroll
        for (int kk = 0; kk < 4; ++kk)
            b[kk] = *(const bf16x8*)(Wpk3 + ((size_t)(ct * 4 + kk) * 64 + lane) * 8);
        f32x4 a0 = {0.f, 0.f, 0.f, 0.f}, a1 = {0.f, 0.f, 0.f, 0.f};
#pragma unroll
        for (int kk = 0; kk < 4; ++kk) {
            a0 = __builtin_amdgcn_mfma_f32_16x16x32_bf16(a[0][kk], b[kk], a0, 0, 0, 0);
            a1 = __builtin_amdgcn_mfma_f32_16x16x32_bf16(a[1][kk], b[kk], a1, 0, 0, 0);
        }
        acc[0][ct] = a0; acc[1][ct] = a1;
    }
    float s[2][4], s2[2][4];
#pragma unroll
    for (int t = 0; t < 2; ++t)
#pragma unroll
        for (int r = 0; r < 4; ++r) { s[t][r] = 0.f; s2[t][r] = 0.f; }
#pragma unroll
    for (int t = 0; t < 2; ++t)
#pragma unroll
        for (int r = 0; r < 4; ++r) {
            int row = min(rbase + t * 16 + (lane >> 4) * 4 + r, NR - 1);
            int n = row / 3;
#pragma unroll
            for (int ct = 0; ct < 8; ++ct) {
                int col = ct * 16 + rlo;
                float dv = acc[t][ct][r] * o[(size_t)n * 384 + col]
                         + agg[(size_t)row * 128 + col];
                acc[t][ct][r] = dv;
                s[t][r] += dv;
                s2[t][r] = fmaf(dv, dv, s2[t][r]);
            }
        }
#pragma unroll
    for (int t = 0; t < 2; ++t)
#pragma unroll
        for (int r = 0; r < 4; ++r) {
#pragma unroll
            for (int m = 1; m < 16; m <<= 1) {
                s[t][r] += __shfl_xor(s[t][r], m, 16);
                s2[t][r] += __shfl_xor(s2[t][r], m, 16);
            }
        }
#pragma unroll
    for (int t = 0; t < 2; ++t)
#pragma unroll
        for (int r = 0; r < 4; ++r) {
            int row = rbase + t * 16 + (lane >> 4) * 4 + r;
            if (row >= NR) continue;
            float mu = s[t][r] * (1.f / 128.f);
            float rstd = rsqrtf(s2[t][r] * (1.f / 128.f) - mu * mu + 1e-5f);
#pragma unroll
            for (int ct = 0; ct < 8; ++ct) {
                int col = ct * 16 + rlo;
                dvn[(size_t)row * 128 + col] =
                    (unsigned short)f2bf(fmaf((acc[t][ct][r] - mu) * rstd, ln_scale[col], ln_bias[col]));
            }
        }
}

extern "C" void kernel_launch(void* const* d_in, const int* in_sizes, int n_in,
                              void* d_out, int out_size, void* d_ws, size_t ws_size,
                              hipStream_t stream) {
    const float* x          = (const float*)d_in[0];
    const float* vec        = (const float*)d_in[1];
    const float* edge_vec   = (const float*)d_in[2];
    const float* edge_weight= (const float*)d_in[3];
    const float* W_fc1      = (const float*)d_in[4];
    const float* W_fcv      = (const float*)d_in[5];
    const float* b_fcv      = (const float*)d_in[6];
    const float* W_fco      = (const float*)d_in[7];
    const float* b_fco      = (const float*)d_in[8];
    const float* W_out      = (const float*)d_in[9];
    const float* W_vecproj  = (const float*)d_in[10];
    const float* W_equiv    = (const float*)d_in[11];
    const float* ln_scale   = (const float*)d_in[12];
    const float* ln_bias    = (const float*)d_in[13];
    const int*   edge_index = (const int*)d_in[14];

    float* out_x   = (float*)d_out;
    float* out_vec = out_x + (size_t)NN * DIM;
    unsigned short* Pb = (unsigned short*)d_out; // N x 512 bf16, alias (dead before out writes)

    float* ws   = (float*)d_ws;
    float* h1   = ws;                          // N*384
    float* pv   = h1 + 11520000;               // N*384
    float* att  = pv + 11520000;               // N*128
    float* vdot = att + 3840000;               // N*128
    float* o    = vdot + 3840000;              // N*384
    float* agg  = o + 11520000;                // 3N*128
    float* kvz  = agg + 11520000;              // 2176
    unsigned short* vp12b = (unsigned short*)o;   // 3N*256 bf16, consumed before o written
    unsigned short* dvnb  = (unsigned short*)pv;  // 3N*128 bf16, pv dead by then
    int* cnt    = (int*)(kvz + 2176);          // N
    int* off    = cnt + NN;                    // N+1
    int* pos    = off + NN + 1;                // N
    int* se     = pos + NN;                    // E
    int* ssrc   = se + EE;                     // E
    size_t woff = ((size_t)(ssrc + EE - (int*)ws) + 3) & ~(size_t)3;   // 16B align
    short* Wpk  = (short*)(ws + woff);         // 448 frags * 512 shorts
    short* pk_fc1  = Wpk;
    short* pk_fcv  = Wpk + 96 * 512;
    short* pk_wout = Wpk + 192 * 512;
    short* pk_vp12 = Wpk + 288 * 512;
    short* pk_vp3  = Wpk + 352 * 512;
    short* pk_fco  = Wpk + 384 * 512;
    short* pk_weq  = Wpk + 416 * 512;

    hipMemsetAsync(kvz, 0, 2176 * sizeof(float), stream);
    hipMemsetAsync(cnt, 0, NN * sizeof(int), stream);

    pack_all<<<112, 256, 0, stream>>>(W_fc1, W_fcv, W_out, W_vecproj, W_fco, W_equiv, Wpk);

    // CSR build (depends only on edge_index)
    hist_kernel<<<(EE + 255) / 256, 256, 0, stream>>>(edge_index, cnt);
    scan_kernel<<<1, 1024, 0, stream>>>(cnt, off, pos);
    scatter_kernel<<<(EE + 255) / 256, 256, 0, stream>>>(edge_index, pos, se, ssrc);

    const int gN = (NN + 127) / 128;           // 235
    const int g3N = (3 * NN + 127) / 128;      // 704
    mfma_gemm<384, false, float, float><<<gN, 256, 0, stream>>>(x, pk_fc1, nullptr, h1, NN);
    mfma_gemm<384, true, float, float><<<gN, 256, 0, stream>>>(x, pk_fcv, b_fcv, pv, NN);
    kv_reduce<<<512, 256, 0, stream>>>(h1, pv, kvz);
    attn_apply<<<NN / 8, 128, 0, stream>>>(h1, kvz, att);
    mfma_gemm<256, false, float, unsigned short><<<g3N, 256, 0, stream>>>(vec, pk_vp12, nullptr, vp12b, 3 * NN);
    vecdot_reduce<<<NN / 8, 128, 0, stream>>>(vp12b, vec, pv, vdot, Pb);
    mfma_gemm<384, false, float, float><<<gN, 256, 0, stream>>>(att, pk_wout, nullptr, o, NN);
    edge_agg_kernel<<<NN, 256, 0, stream>>>(off, ssrc, se, edge_vec, Pb, agg);
    outx_mfma<<<gN, 256, 0, stream>>>(att, vdot, o, pk_fco, b_fco, h1, edge_weight, out_x);
    outvec1<<<g3N, 256, 0, stream>>>(vec, pk_vp3, o, agg, ln_scale, ln_bias, dvnb);
    mfma_gemm<128, false, unsigned short, float><<<g3N, 256, 0, stream>>>(dvnb, pk_weq, nullptr, out_vec, 3 * NN);
}

// Round 6
// 500.364 us; speedup vs baseline: 2.4633x; 1.1996x over previous
//
#include <hip/hip_runtime.h>
#include <math.h>

#define NN 30000
#define EE 480000
#define DIM 128
#define KVB 512   // kv_part blocks

typedef __attribute__((ext_vector_type(8))) short bf16x8;
typedef __attribute__((ext_vector_type(4))) short s16x4;
typedef __attribute__((ext_vector_type(4))) float f32x4;
typedef __attribute__((ext_vector_type(4))) float float4v;

__device__ inline short f2bf(float f) {      // RNE f32 -> bf16
    union { float f; unsigned u; } v; v.f = f;
    unsigned u = v.u;
    u += 0x7fffu + ((u >> 16) & 1u);
    return (short)(u >> 16);
}
__device__ inline float bf2f(unsigned short u) {
    union { unsigned u; float f; } v; v.u = ((unsigned)u) << 16; return v.f;
}

__device__ inline bf16x8 cvt8(float4v lo, float4v hi) {
    bf16x8 r;
    r[0] = f2bf(lo[0]); r[1] = f2bf(lo[1]); r[2] = f2bf(lo[2]); r[3] = f2bf(lo[3]);
    r[4] = f2bf(hi[0]); r[5] = f2bf(hi[1]); r[6] = f2bf(hi[2]); r[7] = f2bf(hi[3]);
    return r;
}

// ---------------- weight pre-pack (fragment-major bf16) ----------------
__global__ void pack_all(const float* __restrict__ fc1, const float* __restrict__ fcv,
                         const float* __restrict__ wout, const float* __restrict__ wvp,
                         const float* __restrict__ fco, const float* __restrict__ weq,
                         short* __restrict__ Wpk) {
    int fid = blockIdx.x * 4 + (threadIdx.x >> 6);
    int lane = threadIdx.x & 63;
    const float* src; int Nsrc, c0, f;
    if (fid < 96)       { src = fc1;  Nsrc = 384; c0 = 0;   f = fid; }
    else if (fid < 192) { src = fcv;  Nsrc = 384; c0 = 0;   f = fid - 96; }
    else if (fid < 288) { src = wout; Nsrc = 384; c0 = 0;   f = fid - 192; }
    else if (fid < 352) { src = wvp;  Nsrc = 384; c0 = 0;   f = fid - 288; }
    else if (fid < 384) { src = wvp;  Nsrc = 384; c0 = 256; f = fid - 352; }
    else if (fid < 416) { src = fco;  Nsrc = 128; c0 = 0;   f = fid - 384; }
    else                { src = weq;  Nsrc = 128; c0 = 0;   f = fid - 416; }
    int ct = f >> 2, kk = f & 3;
    int k0 = kk * 32 + (lane >> 4) * 8;
    int col = c0 + ct * 16 + (lane & 15);
    bf16x8 v;
#pragma unroll
    for (int i = 0; i < 8; ++i) v[i] = f2bf(src[(size_t)(k0 + i) * Nsrc + col]);
    *(bf16x8*)(Wpk + ((size_t)fid * 64 + lane) * 8) = v;
}

// ---------------- generic MFMA GEMM: out[n,:COLS] = in[n,:128] @ W (+bias) ----------------
template<int COLS, bool BIAS, typename InT, typename OutT>
__global__ __launch_bounds__(256) void mfma_gemm(const InT* __restrict__ in,
        const short* __restrict__ Wpk, const float* __restrict__ bias,
        OutT* __restrict__ out, int nrows) {
    const int lane = threadIdx.x & 63;
    const int wid = threadIdx.x >> 6;
    const int rbase = blockIdx.x * 128 + wid * 32;
    if (rbase >= nrows) return;
    const int rlo = lane & 15, khi = (lane >> 4) * 8;
    bf16x8 a[2][4];
#pragma unroll
    for (int t = 0; t < 2; ++t) {
        int row = min(rbase + t * 16 + rlo, nrows - 1);
        const InT* rp = in + (size_t)row * 128 + khi;
#pragma unroll
        for (int kk = 0; kk < 4; ++kk) {
            if constexpr (sizeof(InT) == 4) {
                float4v lo = *(const float4v*)(rp + kk * 32);
                float4v hi = *(const float4v*)(rp + kk * 32 + 4);
                a[t][kk] = cvt8(lo, hi);
            } else {
                a[t][kk] = *(const bf16x8*)(rp + kk * 32);
            }
        }
    }
    for (int ct = 0; ct < COLS / 16; ++ct) {
        bf16x8 b[4];
#pragma unroll
        for (int kk = 0; kk < 4; ++kk)
            b[kk] = *(const bf16x8*)(Wpk + ((size_t)(ct * 4 + kk) * 64 + lane) * 8);
        f32x4 acc0 = {0.f, 0.f, 0.f, 0.f}, acc1 = {0.f, 0.f, 0.f, 0.f};
#pragma unroll
        for (int kk = 0; kk < 4; ++kk) {
            acc0 = __builtin_amdgcn_mfma_f32_16x16x32_bf16(a[0][kk], b[kk], acc0, 0, 0, 0);
            acc1 = __builtin_amdgcn_mfma_f32_16x16x32_bf16(a[1][kk], b[kk], acc1, 0, 0, 0);
        }
        const int col = ct * 16 + rlo;
        const float bv = BIAS ? bias[col] : 0.f;
#pragma unroll
        for (int r = 0; r < 4; ++r) {
            int row0 = rbase + (lane >> 4) * 4 + r;
            int row1 = row0 + 16;
            if constexpr (sizeof(OutT) == 4) {
                if (row0 < nrows) out[(size_t)row0 * COLS + col] = acc0[r] + bv;
                if (row1 < nrows) out[(size_t)row1 * COLS + col] = acc1[r] + bv;
            } else {
                if (row0 < nrows) out[(size_t)row0 * COLS + col] = (OutT)f2bf(acc0[r] + bv);
                if (row1 < nrows) out[(size_t)row1 * COLS + col] = (OutT)f2bf(acc1[r] + bv);
            }
        }
    }
}

// ---------------- kv stage 1: per-block partials, no atomics ----------------
// slab[b][i], i in [0,2176): 2048 kv partials + 128 z partials.
__global__ __launch_bounds__(256) void kv_part(const float* __restrict__ h1,
        const float* __restrict__ pv, float* __restrict__ slab) {
    __shared__ float kf_s[8][DIM];
    __shared__ float v_s[8][DIM];
    const int tid = threadIdx.x;              // 256
    const int rpb = (NN + KVB - 1) / KVB;     // 59
    const int n0 = blockIdx.x * rpb;
    const int n1 = min(n0 + rpb, NN);
    const int base = tid * 8;
    const int hf = base >> 4;
    const int h = hf >> 4;
    const int d0 = base & 15;
    // loader role
    const int lr = tid >> 5;                  // row in tile 0..7
    const int lg = tid & 31;
    const bool isK = lg < 16;
    const int le = (lg & 15) * 8;
    float acc[8];
#pragma unroll
    for (int i = 0; i < 8; ++i) acc[i] = 0.f;
    float zacc = 0.f;
    float4v p0 = {0,0,0,0}, p1 = {0,0,0,0};
    bool pvalid = false;
    // prefetch tile 0
    {
        int n = n0 + lr;
        pvalid = n < n1;
        if (pvalid) {
            const float* src = isK ? (h1 + (size_t)n * 384 + 128 + le)
                                   : (pv + (size_t)n * 384 + le);
            p0 = *(const float4v*)src;
            p1 = *(const float4v*)(src + 4);
        }
    }
    for (int nt = n0; nt < n1; nt += 8) {
        __syncthreads();                       // LDS free from previous compute
        float4v c0 = p0, c1 = p1;
        if (!pvalid) { c0 = {0,0,0,0}; c1 = {0,0,0,0}; }
        else if (isK) {
#pragma unroll
            for (int i = 0; i < 4; ++i) {
                c0[i] = c0[i] > 0.f ? c0[i] + 1.f : expf(c0[i]);
                c1[i] = c1[i] > 0.f ? c1[i] + 1.f : expf(c1[i]);
            }
        }
        float* dst = (isK ? kf_s[lr] : v_s[lr]) + le;
        *(float4v*)dst = c0;
        *(float4v*)(dst + 4) = c1;
        __syncthreads();
        // prefetch next tile (overlaps compute)
        {
            int n = nt + 8 + lr;
            pvalid = n < n1;
            if (pvalid) {
                const float* src = isK ? (h1 + (size_t)n * 384 + 128 + le)
                                       : (pv + (size_t)n * 384 + le);
                p0 = *(const float4v*)src;
                p1 = *(const float4v*)(src + 4);
            }
        }
#pragma unroll
        for (int r = 0; r < 8; ++r) {
            float kfv = kf_s[r][hf];
#pragma unroll
            for (int i = 0; i < 8; ++i) acc[i] = fmaf(kfv, v_s[r][h * 16 + d0 + i], acc[i]);
            if (tid < 128) zacc += kf_s[r][tid];
        }
    }
    float* row = slab + (size_t)blockIdx.x * 2176;
#pragma unroll
    for (int i = 0; i < 8; ++i) row[base + i] = acc[i];
    if (tid < 128) row[2048 + tid] = zacc;
}

// ---------------- kv stage 2: kvz[i] = sum_b slab[b][i] ----------------
__global__ void kv_final(const float* __restrict__ slab, float* __restrict__ kvz) {
    int i = blockIdx.x * 256 + threadIdx.x;
    if (i >= 2176) return;
    float a[8];
#pragma unroll
    for (int j = 0; j < 8; ++j) a[j] = 0.f;
    for (int b = 0; b < KVB; b += 8) {
#pragma unroll
        for (int j = 0; j < 8; ++j) a[j] += slab[(size_t)(b + j) * 2176 + i];
    }
    kvz[i] = ((a[0] + a[1]) + (a[2] + a[3])) + ((a[4] + a[5]) + (a[6] + a[7]));
}

// ---------------- att[n,h*16+d] = (qf . kv) / (qf . z + 1e-6), 8 rows per block ------------
__global__ void attn_apply(const float* __restrict__ h1, const float* __restrict__ kvz,
                           float* __restrict__ att) {
    __shared__ float kv_s[8 * 16 * 17];
    __shared__ float z_s[DIM];
    __shared__ float qf_s[8][DIM];
    const int tid = threadIdx.x;              // 128
    const int n0 = blockIdx.x * 8;
    for (int i = tid; i < 2048; i += 128) {
        int hf = i >> 4, d = i & 15;
        kv_s[hf * 17 + d] = kvz[i];
    }
    z_s[tid] = kvz[2048 + tid];
#pragma unroll
    for (int r = 0; r < 8; ++r) {
        float qv = h1[(size_t)(n0 + r) * 384 + tid];
        qf_s[r][tid] = qv > 0.f ? qv + 1.f : expf(qv);
    }
    __syncthreads();
    const int h = tid >> 4, d = tid & 15;
#pragma unroll
    for (int r = 0; r < 8; ++r) {
        float num = 0.f, den = 0.f;
#pragma unroll
        for (int f = 0; f < 16; ++f) {
            float q = qf_s[r][h * 16 + f];
            num = fmaf(q, kv_s[(h * 16 + f) * 17 + d], num);
            den = fmaf(q, z_s[h * 16 + f], den);
        }
        att[(size_t)(n0 + r) * DIM + tid] = num / (den + 1e-6f);
    }
}

// ---------------- vdot + bf16 P-pack (interleaved layout: P[n][o*4 + {v2,m0,m1,m2}]) ------
__global__ void vecdot_reduce(const unsigned short* __restrict__ vp12,
                              const float* __restrict__ vec, const float* __restrict__ pv,
                              float* __restrict__ vdot, unsigned short* __restrict__ P) {
    const int tid = threadIdx.x;              // 128
    const int n0 = blockIdx.x * 8;
#pragma unroll
    for (int r = 0; r < 8; ++r) {
        int n = n0 + r;
        const unsigned short* vp = vp12 + (size_t)(3 * n) * 256;
        float acc = bf2f(vp[tid]) * bf2f(vp[128 + tid])
                  + bf2f(vp[256 + tid]) * bf2f(vp[384 + tid])
                  + bf2f(vp[512 + tid]) * bf2f(vp[640 + tid]);
        vdot[(size_t)n * DIM + tid] = acc;
        float v1 = pv[(size_t)n * 384 + 128 + tid];
        float v2 = pv[(size_t)n * 384 + 256 + tid];
        s16x4 pk;
        pk[0] = f2bf(v2);
        pk[1] = f2bf(vec[((size_t)n * 3 + 0) * DIM + tid] * v1);
        pk[2] = f2bf(vec[((size_t)n * 3 + 1) * DIM + tid] * v1);
        pk[3] = f2bf(vec[((size_t)n * 3 + 2) * DIM + tid] * v1);
        *(s16x4*)(P + (size_t)n * 512 + tid * 4) = pk;
    }
}

// ---------------- edge CSR build ----------------
__global__ void hist_kernel(const int* __restrict__ eidx, int* __restrict__ cnt) {
    int e = blockIdx.x * 256 + threadIdx.x;
    if (e < EE) atomicAdd(&cnt[eidx[EE + e]], 1);
}

__global__ void scan_kernel(const int* __restrict__ cnt, int* __restrict__ off,
                            int* __restrict__ pos) {
    __shared__ int wsum[16];
    const int tid = threadIdx.x;              // 1024
    const int lane = tid & 63, wv = tid >> 6;
    const int PER = 30;
    const int base = tid * PER;
    int local[PER];
    int s = 0;
#pragma unroll
    for (int i = 0; i < PER; ++i) {
        int idx = base + i;
        int c = (idx < NN) ? cnt[idx] : 0;
        local[i] = s;
        s += c;
    }
    int incl = s;
#pragma unroll
    for (int d = 1; d < 64; d <<= 1) {
        int v = __shfl_up(incl, d, 64);
        if (lane >= d) incl += v;
    }
    if (lane == 63) wsum[wv] = incl;
    __syncthreads();
    if (wv == 0 && lane < 16) {
        int v = wsum[lane];
        int iv = v;
#pragma unroll
        for (int d = 1; d < 16; d <<= 1) {
            int u = __shfl_up(iv, d, 16);
            if (lane >= d) iv += u;
        }
        wsum[lane] = iv - v;
    }
    __syncthreads();
    const int carry = wsum[wv] + (incl - s);
#pragma unroll
    for (int i = 0; i < PER; ++i) {
        int idx = base + i;
        if (idx < NN) {
            int v = carry + local[i];
            off[idx] = v;
            pos[idx] = v;
        }
    }
    if (tid == 1023) off[NN] = wsum[15] + incl;
}

__global__ void scatter_kernel(const int* __restrict__ eidx, int* __restrict__ pos,
                               int* __restrict__ se, int* __restrict__ ssrc) {
    int e = blockIdx.x * 256 + threadIdx.x;
    if (e >= EE) return;
    int dst = eidx[EE + e];
    int p = atomicAdd(&pos[dst], 1);
    se[p] = e;
    ssrc[p] = eidx[e];
}

// ---------------- segmented gather-reduce: one block (2 groups) per dst --------------------
__global__ __launch_bounds__(256) void edge_agg_kernel(
        const int* __restrict__ off, const int* __restrict__ ssrc,
        const int* __restrict__ se, const float* __restrict__ evec,
        const unsigned short* __restrict__ P, float* __restrict__ agg) {
    __shared__ int srcs[128];
    __shared__ float evs[3][128];
    __shared__ float part[3][128];
    const int dst = blockIdx.x;
    const int tid = threadIdx.x;              // 256
    const int g = tid >> 7, o = tid & 127;
    const int j0 = off[dst], j1 = off[dst + 1];
    float a0 = 0.f, a1 = 0.f, a2 = 0.f;
    for (int jt = j0; jt < j1; jt += 128) {
        const int m = min(128, j1 - jt);
        if (tid < m) {
            srcs[tid] = ssrc[jt + tid];
            int e = se[jt + tid];
            evs[0][tid] = evec[(size_t)e * 3 + 0];
            evs[1][tid] = evec[(size_t)e * 3 + 1];
            evs[2][tid] = evec[(size_t)e * 3 + 2];
        }
        __syncthreads();
        for (int jj = g; jj < m; jj += 2) {
            s16x4 pk = *(const s16x4*)(P + (size_t)srcs[jj] * 512 + o * 4);
            float v2 = bf2f((unsigned short)pk[0]);
            a0 += fmaf(evs[0][jj], v2, bf2f((unsigned short)pk[1]));
            a1 += fmaf(evs[1][jj], v2, bf2f((unsigned short)pk[2]));
            a2 += fmaf(evs[2][jj], v2, bf2f((unsigned short)pk[3]));
        }
        __syncthreads();
    }
    if (g == 1) { part[0][o] = a0; part[1][o] = a1; part[2][o] = a2; }
    __syncthreads();
    if (g == 0) {
        a0 += part[0][o]; a1 += part[1][o]; a2 += part[2][o];
        agg[((size_t)dst * 3 + 0) * DIM + o] = a0;
        agg[((size_t)dst * 3 + 1) * DIM + o] = a1;
        agg[((size_t)dst * 3 + 2) * DIM + o] = a2;
    }
}

// ---------------- out_x = non_att + ((att + vdot*o2 + o3) @ W_fco + b_fco)*ew (MFMA) ------
__global__ __launch_bounds__(256) void outx_mfma(const float* __restrict__ att,
        const float* __restrict__ vdot, const float* __restrict__ o,
        const short* __restrict__ Wpk, const float* __restrict__ bfco,
        const float* __restrict__ h1, const float* __restrict__ ew,
        float* __restrict__ outx) {
    const int lane = threadIdx.x & 63;
    const int wid = threadIdx.x >> 6;
    const int rbase = blockIdx.x * 128 + wid * 32;
    if (rbase >= NN) return;
    const int rlo = lane & 15, khi = (lane >> 4) * 8;
    bf16x8 a[2][4];
#pragma unroll
    for (int t = 0; t < 2; ++t) {
        int row = min(rbase + t * 16 + rlo, NN - 1);
        const float* pa = att + (size_t)row * 128 + khi;
        const float* pd = vdot + (size_t)row * 128 + khi;
        const float* po = o + (size_t)row * 384 + khi;
#pragma unroll
        for (int kk = 0; kk < 4; ++kk) {
            int kb = kk * 32;
            float4v al = *(const float4v*)(pa + kb), ah = *(const float4v*)(pa + kb + 4);
            float4v dl = *(const float4v*)(pd + kb), dh = *(const float4v*)(pd + kb + 4);
            float4v o2l = *(const float4v*)(po + kb + 128), o2h = *(const float4v*)(po + kb + 132);
            float4v o3l = *(const float4v*)(po + kb + 256), o3h = *(const float4v*)(po + kb + 260);
            a[t][kk] = cvt8(al + dl * o2l + o3l, ah + dh * o2h + o3h);
        }
    }
    float ewv[2][4];
#pragma unroll
    for (int t = 0; t < 2; ++t)
#pragma unroll
        for (int r = 0; r < 4; ++r)
            ewv[t][r] = ew[min(rbase + t * 16 + (lane >> 4) * 4 + r, NN - 1)];
    for (int ct = 0; ct < 8; ++ct) {
        bf16x8 b[4];
#pragma unroll
        for (int kk = 0; kk < 4; ++kk)
            b[kk] = *(const bf16x8*)(Wpk + ((size_t)(ct * 4 + kk) * 64 + lane) * 8);
        f32x4 acc0 = {0.f, 0.f, 0.f, 0.f}, acc1 = {0.f, 0.f, 0.f, 0.f};
#pragma unroll
        for (int kk = 0; kk < 4; ++kk) {
            acc0 = __builtin_amdgcn_mfma_f32_16x16x32_bf16(a[0][kk], b[kk], acc0, 0, 0, 0);
            acc1 = __builtin_amdgcn_mfma_f32_16x16x32_bf16(a[1][kk], b[kk], acc1, 0, 0, 0);
        }
        const int col = ct * 16 + rlo;
        const float bv = bfco[col];
#pragma unroll
        for (int r = 0; r < 4; ++r) {
            int row0 = rbase + (lane >> 4) * 4 + r;
            if (row0 < NN)
                outx[(size_t)row0 * 128 + col] =
                    h1[(size_t)row0 * 384 + 256 + col] + (acc0[r] + bv) * ewv[0][r];
            int row1 = row0 + 16;
            if (row1 < NN)
                outx[(size_t)row1 * 128 + col] =
                    h1[(size_t)row1 * 384 + 256 + col] + (acc1[r] + bv) * ewv[1][r];
        }
    }
}

// ---------------- outvec part1: dvn(bf16) = LN(v3p*o1 + agg) ----------------
__global__ __launch_bounds__(256) void outvec1(const float* __restrict__ vec,
        const short* __restrict__ Wpk3, const float* __restrict__ o,
        const float* __restrict__ agg, const float* __restrict__ ln_scale,
        const float* __restrict__ ln_bias, unsigned short* __restrict__ dvn) {
    const int NR = 3 * NN;
    const int lane = threadIdx.x & 63;
    const int wid = threadIdx.x >> 6;
    const int rbase = blockIdx.x * 128 + wid * 32;
    if (rbase >= NR) return;
    const int rlo = lane & 15, khi = (lane >> 4) * 8;
    bf16x8 a[2][4];
#pragma unroll
    for (int t = 0; t < 2; ++t) {
        int row = min(rbase + t * 16 + rlo, NR - 1);
        const float* rp = vec + (size_t)row * 128 + khi;
#pragma unroll
        for (int kk = 0; kk < 4; ++kk) {
            float4v lo = *(const float4v*)(rp + kk * 32);
            float4v hi = *(const float4v*)(rp + kk * 32 + 4);
            a[t][kk] = cvt8(lo, hi);
        }
    }
    f32x4 acc[2][8];
#pragma unroll
    for (int ct = 0; ct < 8; ++ct) {
        bf16x8 b[4];
#pragma unroll
        for (int kk = 0; kk < 4; ++kk)
            b[kk] = *(const bf16x8*)(Wpk3 + ((size_t)(ct * 4 + kk) * 64 + lane) * 8);
        f32x4 a0 = {0.f, 0.f, 0.f, 0.f}, a1 = {0.f, 0.f, 0.f, 0.f};
#pragma unroll
        for (int kk = 0; kk < 4; ++kk) {
            a0 = __builtin_amdgcn_mfma_f32_16x16x32_bf16(a[0][kk], b[kk], a0, 0, 0, 0);
            a1 = __builtin_amdgcn_mfma_f32_16x16x32_bf16(a[1][kk], b[kk], a1, 0, 0, 0);
        }
        acc[0][ct] = a0; acc[1][ct] = a1;
    }
    float s[2][4], s2[2][4];
#pragma unroll
    for (int t = 0; t < 2; ++t)
#pragma unroll
        for (int r = 0; r < 4; ++r) { s[t][r] = 0.f; s2[t][r] = 0.f; }
#pragma unroll
    for (int t = 0; t < 2; ++t)
#pragma unroll
        for (int r = 0; r < 4; ++r) {
            int row = min(rbase + t * 16 + (lane >> 4) * 4 + r, NR - 1);
            int n = row / 3;
#pragma unroll
            for (int ct = 0; ct < 8; ++ct) {
                int col = ct * 16 + rlo;
                float dv = acc[t][ct][r] * o[(size_t)n * 384 + col]
                         + agg[(size_t)row * 128 + col];
                acc[t][ct][r] = dv;
                s[t][r] += dv;
                s2[t][r] = fmaf(dv, dv, s2[t][r]);
            }
        }
#pragma unroll
    for (int t = 0; t < 2; ++t)
#pragma unroll
        for (int r = 0; r < 4; ++r) {
#pragma unroll
            for (int m = 1; m < 16; m <<= 1) {
                s[t][r] += __shfl_xor(s[t][r], m, 16);
                s2[t][r] += __shfl_xor(s2[t][r], m, 16);
            }
        }
#pragma unroll
    for (int t = 0; t < 2; ++t)
#pragma unroll
        for (int r = 0; r < 4; ++r) {
            int row = rbase + t * 16 + (lane >> 4) * 4 + r;
            if (row >= NR) continue;
            float mu = s[t][r] * (1.f / 128.f);
            float rstd = rsqrtf(s2[t][r] * (1.f / 128.f) - mu * mu + 1e-5f);
#pragma unroll
            for (int ct = 0; ct < 8; ++ct) {
                int col = ct * 16 + rlo;
                dvn[(size_t)row * 128 + col] =
                    (unsigned short)f2bf(fmaf((acc[t][ct][r] - mu) * rstd, ln_scale[col], ln_bias[col]));
            }
        }
}

extern "C" void kernel_launch(void* const* d_in, const int* in_sizes, int n_in,
                              void* d_out, int out_size, void* d_ws, size_t ws_size,
                              hipStream_t stream) {
    const float* x          = (const float*)d_in[0];
    const float* vec        = (const float*)d_in[1];
    const float* edge_vec   = (const float*)d_in[2];
    const float* edge_weight= (const float*)d_in[3];
    const float* W_fc1      = (const float*)d_in[4];
    const float* W_fcv      = (const float*)d_in[5];
    const float* b_fcv      = (const float*)d_in[6];
    const float* W_fco      = (const float*)d_in[7];
    const float* b_fco      = (const float*)d_in[8];
    const float* W_out      = (const float*)d_in[9];
    const float* W_vecproj  = (const float*)d_in[10];
    const float* W_equiv    = (const float*)d_in[11];
    const float* ln_scale   = (const float*)d_in[12];
    const float* ln_bias    = (const float*)d_in[13];
    const int*   edge_index = (const int*)d_in[14];

    float* out_x   = (float*)d_out;
    float* out_vec = out_x + (size_t)NN * DIM;
    unsigned short* Pb = (unsigned short*)d_out; // N x 512 bf16, alias (dead before out writes)

    float* ws   = (float*)d_ws;
    float* h1   = ws;                          // N*384
    float* pv   = h1 + 11520000;               // N*384
    float* att  = pv + 11520000;               // N*128
    float* vdot = att + 3840000;               // N*128
    float* o    = vdot + 3840000;              // N*384
    float* agg  = o + 11520000;                // 3N*128
    float* kvz  = agg + 11520000;              // 2176
    unsigned short* vp12b = (unsigned short*)o;   // 3N*256 bf16, consumed before o written
    unsigned short* dvnb  = (unsigned short*)pv;  // 3N*128 bf16, pv dead by then
    float* slab = agg;                         // KVB*2176 f32, dead before edge_agg writes agg
    int* cnt    = (int*)(kvz + 2176);          // N
    int* off    = cnt + NN;                    // N+1
    int* pos    = off + NN + 1;                // N
    int* se     = pos + NN;                    // E
    int* ssrc   = se + EE;                     // E
    size_t woff = ((size_t)(ssrc + EE - (int*)ws) + 3) & ~(size_t)3;   // 16B align
    short* Wpk  = (short*)(ws + woff);         // 448 frags * 512 shorts
    short* pk_fc1  = Wpk;
    short* pk_fcv  = Wpk + 96 * 512;
    short* pk_wout = Wpk + 192 * 512;
    short* pk_vp12 = Wpk + 288 * 512;
    short* pk_vp3  = Wpk + 352 * 512;
    short* pk_fco  = Wpk + 384 * 512;
    short* pk_weq  = Wpk + 416 * 512;

    hipMemsetAsync(cnt, 0, NN * sizeof(int), stream);

    pack_all<<<112, 256, 0, stream>>>(W_fc1, W_fcv, W_out, W_vecproj, W_fco, W_equiv, Wpk);

    // CSR build (depends only on edge_index)
    hist_kernel<<<(EE + 255) / 256, 256, 0, stream>>>(edge_index, cnt);
    scan_kernel<<<1, 1024, 0, stream>>>(cnt, off, pos);
    scatter_kernel<<<(EE + 255) / 256, 256, 0, stream>>>(edge_index, pos, se, ssrc);

    const int gN = (NN + 127) / 128;           // 235
    const int g3N = (3 * NN + 127) / 128;      // 704
    mfma_gemm<384, false, float, float><<<gN, 256, 0, stream>>>(x, pk_fc1, nullptr, h1, NN);
    mfma_gemm<384, true, float, float><<<gN, 256, 0, stream>>>(x, pk_fcv, b_fcv, pv, NN);
    kv_part<<<KVB, 256, 0, stream>>>(h1, pv, slab);
    kv_final<<<9, 256, 0, stream>>>(slab, kvz);
    attn_apply<<<NN / 8, 128, 0, stream>>>(h1, kvz, att);
    mfma_gemm<256, false, float, unsigned short><<<g3N, 256, 0, stream>>>(vec, pk_vp12, nullptr, vp12b, 3 * NN);
    vecdot_reduce<<<NN / 8, 128, 0, stream>>>(vp12b, vec, pv, vdot, Pb);
    mfma_gemm<384, false, float, float><<<gN, 256, 0, stream>>>(att, pk_wout, nullptr, o, NN);
    edge_agg_kernel<<<NN, 256, 0, stream>>>(off, ssrc, se, edge_vec, Pb, agg);
    outx_mfma<<<gN, 256, 0, stream>>>(att, vdot, o, pk_fco, b_fco, h1, edge_weight, out_x);
    outvec1<<<g3N, 256, 0, stream>>>(vec, pk_vp3, o, agg, ln_scale, ln_bias, dvnb);
    mfma_gemm<128, false, unsigned short, float><<<g3N, 256, 0, stream>>>(dvnb, pk_weq, nullptr, out_vec, 3 * NN);
}